// Round 7
// baseline (292.001 us; speedup 1.0000x reference)
//
#include <hip/hip_runtime.h>
#include <math.h>

#define E_N   8192
#define HID   128
#define NRAD  64
#define KNB   32
#define CUTF  10.0f
#define LNEPS 1e-5f

typedef unsigned short u16;
typedef unsigned int   u32;
typedef unsigned long long u64;
typedef __bf16 bf16x8 __attribute__((ext_vector_type(8)));
typedef u16    u16x8  __attribute__((ext_vector_type(8)));
typedef float  f32x4  __attribute__((ext_vector_type(4)));

__device__ __forceinline__ u16 f2bf(float f) {
  unsigned u = __float_as_uint(f);
  unsigned r = (u + 0x7fffu + ((u >> 16) & 1u)) >> 16;   // RNE
  return (u16)r;
}

__device__ __forceinline__ u64 shflx64(u64 v, int m) {
  int lo = __shfl_xor((int)(v & 0xffffffffull), m, 64);
  int hi = __shfl_xor((int)(v >> 32), m, 64);
  return ((u64)(unsigned)hi << 32) | (unsigned)lo;
}

// ---------------- kernel 0a: bf16 weight prep (rbf block of W1, W2), transposed ----------------
__global__ void k_convw(const float* __restrict__ W1, const float* __restrict__ W2,
                        u16* __restrict__ Wt1r, u16* __restrict__ Wt2) {
  int b = blockIdx.x;            // output col 0..127
  int t = threadIdx.x;           // 0..191
  if (t < 64)       Wt1r[b*64 + t]        = f2bf(W1[(256+t)*HID + b]);   // rbf rows 256..319
  else if (t < 192) Wt2[b*HID + (t-64)]   = f2bf(W2[(t-64)*HID + b]);
}

// ---------------- kernel 0b: fused weight products Wqc = Wq@W1[0:128], Wkc = Wk@W1[128:256] ----------------
__global__ void k_fusew(const float* __restrict__ Wq, const float* __restrict__ Wk,
                        const float* __restrict__ W1,
                        float* __restrict__ Wqc, float* __restrict__ Wkc) {
  int r = blockIdx.x, o = threadIdx.x;   // 128 x 128
  float a = 0.f, b = 0.f;
  #pragma unroll 8
  for (int m = 0; m < 128; ++m) {
    a = fmaf(Wq[r*128+m], W1[m*128+o], a);
    b = fmaf(Wk[r*128+m], W1[(128+m)*128+o], b);
  }
  Wqc[r*128+o] = a; Wkc[r*128+o] = b;
}

// ---------------- kernel 1: edge centers + squared norms (packed float4) ----------------
__global__ void k_prep(const float* __restrict__ nc, const int* __restrict__ ei,
                       float4* __restrict__ cen4) {
  int e = blockIdx.x * 256 + threadIdx.x;
  if (e >= E_N) return;
  int a = ei[e], b = ei[E_N + e];
  float x = (nc[a*3+0] + nc[b*3+0]) * 0.5f;
  float y = (nc[a*3+1] + nc[b*3+1]) * 0.5f;
  float z = (nc[a*3+2] + nc[b*3+2]) * 0.5f;
  cen4[e] = make_float4(x, y, z, x*x + y*y + z*z);
}

// ---------------- kernel 2: top-K via ballot-bisect bound + exact lex rank ----------------
// 1 row/block, 256 threads, keys in 32 VGPRs. U = exact 32nd-smallest of the
// 256 per-thread mins (>= T: at most 31 keys are < T, hence at most 31
// thread-mins are < T), found by radix-bisection on key bits using wave
// ballots (no LDS rank loop), rounded up to bit-15 granularity. Survivors
// (key <= U) provably contain the exact top-32; exact (key, idx) lex ranking
// on survivors matches jax.lax.top_k tie order. Fallback guards overflow.
__global__ __launch_bounds__(256) void k_topk(const float4* __restrict__ cen4,
                                              int* __restrict__ idxo) {
  const int row = blockIdx.x;
  const int t = threadIdx.x;
  const int lane = t & 63, w = t >> 6;
  __shared__ u32 cnt4[2][4];
  __shared__ __align__(16) u64 comp[2048];     // 16 KiB survivor buffer
  __shared__ u64 wred[4];
  __shared__ u64 winner;
  __shared__ u32 scnt;

  const float4 me = cen4[row];
  u32 keys[32];
  u32 mn = 0xFFFFFFFFu;
  #pragma unroll
  for (int s = 0; s < 32; ++s) {
    int j = t + (s << 8);
    float4 c = cen4[j];
    float dot = me.x*c.x + me.y*c.y + me.z*c.z;
    float d2 = (me.w + c.w) - 2.0f*dot;       // identical to reference gram trick
    unsigned u = __float_as_uint(d2);
    u = u ^ (((u32)((int)u >> 31)) | 0x80000000u);   // monotone map
    keys[s] = u; mn = u < mn ? u : mn;
  }
  if (t == 0) scnt = 0;

  // --- radix bisect for the exact 32nd-smallest of the 256 mins ---
  u32 prefix = 0;
  u32 rem = 31;
  #pragma unroll 1
  for (int b = 31; b >= 15; --b) {
    bool act = (b == 31) ? true : ((mn >> (b + 1)) == prefix);
    bool z = ((mn >> b) & 1u) == 0u;
    u64 bal = __ballot(act && z);
    if (lane == 0) cnt4[b & 1][w] = (u32)__popcll(bal);
    __syncthreads();
    u32 c0 = cnt4[b&1][0] + cnt4[b&1][1] + cnt4[b&1][2] + cnt4[b&1][3];
    prefix <<= 1;
    if (rem < c0) { /* bit = 0 */ }
    else { prefix |= 1u; rem -= c0; }
  }
  const u32 U = (prefix << 15) | 0x7FFFu;     // inclusive bucket upper edge >= T

  // --- compact survivors (key <= U) ---
  #pragma unroll
  for (int s = 0; s < 32; ++s) {
    if (keys[s] <= U) {
      u32 pos = atomicAdd(&scnt, 1u);
      if (pos < 2048u) comp[pos] = (((u64)keys[s]) << 13) | (u32)(t + (s << 8));
    }
  }
  __syncthreads();
  const int cnt = (int)scnt;      // block-uniform

  if (cnt <= 2048) {
    // exact lex ranking on survivors (vectorized u64-pair reads)
    for (int i = t; i < cnt; i += 256) {
      u64 mev = comp[i];
      int rk = 0;
      int j2 = 0;
      for (; j2 + 2 <= cnt; j2 += 2) {
        ulonglong2 pr = *(const ulonglong2*)&comp[j2];
        rk += (pr.x < mev) ? 1 : 0;
        rk += (pr.y < mev) ? 1 : 0;
      }
      if (j2 < cnt) rk += (comp[j2] < mev) ? 1 : 0;
      if (rk < KNB) idxo[row*KNB + rk] = (int)(mev & 0x1FFFull);
    }
  } else {
    // overflow fallback (correctness guard; statistically never taken):
    // 32 rounds of block-wide min extraction on packed (key, idx)
    u64 lk = 0xFFFFFFFFFFFFFFFFull;
    #pragma unroll
    for (int s = 0; s < 32; ++s) {
      u64 kk = (((u64)keys[s]) << 13) | (u32)(t + (s << 8));
      lk = kk < lk ? kk : lk;
    }
    for (int kk2 = 0; kk2 < KNB; ++kk2) {
      u64 r2 = lk;
      #pragma unroll
      for (int m = 1; m < 64; m <<= 1) {
        u64 o = shflx64(r2, m);
        r2 = o < r2 ? o : r2;
      }
      if (lane == 0) wred[w] = r2;
      __syncthreads();
      if (t == 0) {
        u64 w0 = wred[0] < wred[1] ? wred[0] : wred[1];
        u64 w1 = wred[2] < wred[3] ? wred[2] : wred[3];
        winner = w0 < w1 ? w0 : w1;
        idxo[row*KNB + kk2] = (int)(winner & 0x1FFFull);
      }
      __syncthreads();
      u64 jw = winner & 0x1FFFull;
      if (((u32)jw & 255u) == (u32)t) {
        keys[(int)(jw >> 8)] = 0xFFFFFFFFu;
        lk = 0xFFFFFFFFFFFFFFFFull;
        #pragma unroll
        for (int s = 0; s < 32; ++s) {
          u64 kx = (((u64)keys[s]) << 13) | (u32)(t + (s << 8));
          lk = kx < lk ? kx : lk;
        }
      }
      __syncthreads();
    }
  }
}

// ---------------- kernel 3: q,k,v + fused-projection rows + gates, 8 edges/block ----------------
__global__ __launch_bounds__(128) void k_qkv(const float* __restrict__ ef,
    const float* __restrict__ Wq, const float* __restrict__ Wk, const float* __restrict__ Wv,
    const float* __restrict__ Wqc, const float* __restrict__ Wkc, const float* __restrict__ b1,
    const float* __restrict__ Wg1, const float* __restrict__ bg1,
    const float* __restrict__ Wg2, const float* __restrict__ bg2,
    float* __restrict__ qf, float* __restrict__ kf, float* __restrict__ vf,
    float* __restrict__ qW1, float* __restrict__ kW1, float* __restrict__ gates) {
  const int o = threadIdx.x;
  const int e0 = blockIdx.x * 8;
  __shared__ float efs[8][128];
  __shared__ float vs[8][128];
  __shared__ float gred[8][2];

  #pragma unroll
  for (int e = 0; e < 8; ++e) efs[e][o] = ef[(e0+e)*HID + o];
  __syncthreads();

  float aq[8] = {0}, ak[8] = {0}, av[8] = {0}, aqc[8] = {0}, akc[8] = {0};
  #pragma unroll 4
  for (int d = 0; d < 128; ++d) {
    float wq = Wq[d*128+o], wk = Wk[d*128+o], wv = Wv[d*128+o];
    float wc1 = Wqc[d*128+o], wc2 = Wkc[d*128+o];
    #pragma unroll
    for (int e = 0; e < 8; ++e) {
      float a = efs[e][d];
      aq[e]  = fmaf(a, wq,  aq[e]);
      ak[e]  = fmaf(a, wk,  ak[e]);
      av[e]  = fmaf(a, wv,  av[e]);
      aqc[e] = fmaf(a, wc1, aqc[e]);
      akc[e] = fmaf(a, wc2, akc[e]);
    }
  }
  float bb1 = b1[o];
  #pragma unroll
  for (int e = 0; e < 8; ++e) {
    qf[(e0+e)*HID+o] = aq[e]; kf[(e0+e)*HID+o] = ak[e]; vf[(e0+e)*HID+o] = av[e];
    qW1[(e0+e)*HID+o] = aqc[e] + bb1;
    kW1[(e0+e)*HID+o] = akc[e];
    vs[e][o] = av[e];
  }
  __syncthreads();

  float ag[8] = {0};
  #pragma unroll 4
  for (int d = 0; d < 128; ++d) {
    float wg = Wg1[d*128+o];
    #pragma unroll
    for (int e = 0; e < 8; ++e) ag[e] = fmaf(vs[e][d], wg, ag[e]);
  }
  float bgo = bg1[o], w2 = Wg2[o];
  const int lane = o & 63, w = o >> 6;
  #pragma unroll
  for (int e = 0; e < 8; ++e) {
    float g = ag[e] + bgo;
    g = g / (1.0f + __expf(-g));
    float part = g * w2;
    #pragma unroll
    for (int m = 1; m < 64; m <<= 1) part += __shfl_xor(part, m, 64);
    if (lane == 0) gred[e][w] = part;
  }
  __syncthreads();
  if (o < 8) gates[e0+o] = 1.0f / (1.0f + __expf(-(gred[o][0] + gred[o][1] + bg2[0])));
}

// ---------------- kernel 5: fused attention MLP -> scores (bf16 MFMA, geom folded in) ----------------
__global__ __launch_bounds__(256) void k_mlp(
    const int* __restrict__ idx,
    const float* __restrict__ qf, const float* __restrict__ kf,
    const float4* __restrict__ cen4,
    const float* __restrict__ qW1, const float* __restrict__ kW1,
    const u16* __restrict__ Wt1r, const u16* __restrict__ Wt2,
    const float* __restrict__ W1,           // for w320 row
    const float* __restrict__ b2, const float* __restrict__ W3,
    const float* __restrict__ b3,
    const float* __restrict__ centers, const float* __restrict__ widths,
    float* __restrict__ scores) {
  __shared__ u16 sA[64*64];       // rbf tile, swizzled (8 KiB)
  __shared__ u16 sH[64*128];      // h tile, swizzled (16 KiB)
  __shared__ float spart[4][64];
  __shared__ float sQW[2][128];
  __shared__ float sDot[64];
  __shared__ float sDist[64];
  __shared__ int   sIdx[64];

  const int t  = threadIdx.x;
  const int w  = t >> 6, l = t & 63;
  const int l15 = l & 15, l4 = l >> 4;
  const int rowbase = blockIdx.x * 64;
  const int eBase = rowbase >> 5;           // two edges per block

  // ---- stage: dot + dist + rbf tile + per-edge qW1 rows ----
  const int srow = t >> 2, sb = t & 3;
  const int sp = rowbase + srow;
  const int se = sp >> 5;
  const int sj = idx[sp];
  // q.k dot (4 threads per row, 32 MACs each)
  const float4* q4 = (const float4*)(qf + (size_t)se*HID) + sb*8;
  const float4* k4 = (const float4*)(kf + (size_t)sj*HID) + sb*8;
  float dt = 0.f;
  #pragma unroll
  for (int i = 0; i < 8; ++i) {
    float4 a = q4[i], b = k4[i];
    dt += a.x*b.x + a.y*b.y + a.z*b.z + a.w*b.w;
  }
  dt += __shfl_xor(dt, 1, 64);
  dt += __shfl_xor(dt, 2, 64);
  // geometry
  float4 ce = cen4[se], cj = cen4[sj];
  float ddx = ce.x - cj.x, ddy = ce.y - cj.y, ddz = ce.z - cj.z;
  const float sdist = sqrtf(ddx*ddx + ddy*ddy + ddz*ddz);
  const float sincut = (sdist <= CUTF) ? 1.0f : 0.0f;
  if (sb == 0) { sDot[srow] = dt; sDist[srow] = sdist; }
  {
    u16 tmp[16];
    #pragma unroll
    for (int i4 = 0; i4 < 4; ++i4) {
      float4 cc = *(const float4*)(centers + sb*16 + i4*4);
      float4 ww = *(const float4*)(widths  + sb*16 + i4*4);
      float c4[4] = {cc.x,cc.y,cc.z,cc.w}, w4[4] = {ww.x,ww.y,ww.z,ww.w};
      #pragma unroll
      for (int jj = 0; jj < 4; ++jj) {
        float df = sdist - c4[jj];
        tmp[i4*4+jj] = f2bf(__expf(-w4[jj]*df*df) * sincut);
      }
    }
    #pragma unroll
    for (int g = 0; g < 2; ++g) {
      u16x8 vv;
      #pragma unroll
      for (int jj = 0; jj < 8; ++jj) vv[jj] = tmp[g*8+jj];
      int widx = (srow*64 + sb*16 + g*8) ^ ((srow & 7) << 3);
      *(u16x8*)(&sA[widx]) = vv;
    }
  }
  sQW[t >> 7][t & 127] = qW1[(size_t)(eBase + (t >> 7))*HID + (t & 127)];
  if (t < 64) sIdx[t] = idx[rowbase + t];
  __syncthreads();

  f32x4 acc[4][2];
  #pragma unroll
  for (int rt = 0; rt < 4; ++rt)
    #pragma unroll
    for (int ct = 0; ct < 2; ++ct) acc[rt][ct] = (f32x4){0.f,0.f,0.f,0.f};

  // ---- GEMM1: rbf (K=64) ----
  #pragma unroll
  for (int ks = 0; ks < 2; ++ks) {
    bf16x8 af[4], bfr[2];
    #pragma unroll
    for (int rt = 0; rt < 4; ++rt) {
      int row = rt*16 + l15;
      int aidx = (row*64 + ks*32 + l4*8) ^ ((row & 7) << 3);
      af[rt] = *(const bf16x8*)(&sA[aidx]);
    }
    #pragma unroll
    for (int ct = 0; ct < 2; ++ct) {
      int col = w*32 + ct*16 + l15;
      bfr[ct] = *(const bf16x8*)(&Wt1r[col*64 + ks*32 + l4*8]);
    }
    #pragma unroll
    for (int rt = 0; rt < 4; ++rt)
      #pragma unroll
      for (int ct = 0; ct < 2; ++ct)
        acc[rt][ct] = __builtin_amdgcn_mfma_f32_16x16x32_bf16(af[rt], bfr[ct], acc[rt][ct], 0, 0, 0);
  }

  // ---- epilogue 1: + qW1[e] + kW1[j] + dot*w320, silu -> sH bf16 (swizzled) ----
  {
    float w320[2];
    #pragma unroll
    for (int ct = 0; ct < 2; ++ct) {
      int col = w*32 + ct*16 + l15;
      w320[ct] = W1[320*HID + col];
    }
    #pragma unroll
    for (int rt = 0; rt < 4; ++rt) {
      #pragma unroll
      for (int r = 0; r < 4; ++r) {
        int row = rt*16 + l4*4 + r;
        float dv = sDot[row];
        int jrow = sIdx[row];
        int eh = row >> 5;
        #pragma unroll
        for (int ct = 0; ct < 2; ++ct) {
          int col = w*32 + ct*16 + l15;
          float x = acc[rt][ct][r] + sQW[eh][col] + kW1[(size_t)jrow*HID + col] + dv*w320[ct];
          float h = x / (1.0f + __expf(-x));
          sH[(row*128 + col) ^ ((row & 7) << 3)] = f2bf(h);
        }
      }
    }
  }
  __syncthreads();

  #pragma unroll
  for (int rt = 0; rt < 4; ++rt)
    #pragma unroll
    for (int ct = 0; ct < 2; ++ct) acc[rt][ct] = (f32x4){0.f,0.f,0.f,0.f};

  // ---- GEMM2: h @ W2 ----
  #pragma unroll
  for (int ks = 0; ks < 4; ++ks) {
    bf16x8 af[4], bfr[2];
    #pragma unroll
    for (int rt = 0; rt < 4; ++rt) {
      int row = rt*16 + l15;
      int aidx = (row*128 + ks*32 + l4*8) ^ ((row & 7) << 3);
      af[rt] = *(const bf16x8*)(&sH[aidx]);
    }
    #pragma unroll
    for (int ct = 0; ct < 2; ++ct) {
      int col = w*32 + ct*16 + l15;
      bfr[ct] = *(const bf16x8*)(&Wt2[col*128 + ks*32 + l4*8]);
    }
    #pragma unroll
    for (int rt = 0; rt < 4; ++rt)
      #pragma unroll
      for (int ct = 0; ct < 2; ++ct)
        acc[rt][ct] = __builtin_amdgcn_mfma_f32_16x16x32_bf16(af[rt], bfr[ct], acc[rt][ct], 0, 0, 0);
  }

  // ---- epilogue 2: silu, dot W3, reduce ----
  {
    float b2r[2], w3r[2];
    #pragma unroll
    for (int ct = 0; ct < 2; ++ct) {
      int col = w*32 + ct*16 + l15;
      b2r[ct] = b2[col]; w3r[ct] = W3[col];
    }
    #pragma unroll
    for (int rt = 0; rt < 4; ++rt) {
      #pragma unroll
      for (int r = 0; r < 4; ++r) {
        float part = 0.f;
        #pragma unroll
        for (int ct = 0; ct < 2; ++ct) {
          float x = acc[rt][ct][r] + b2r[ct];
          float h = x / (1.0f + __expf(-x));
          part = fmaf(h, w3r[ct], part);
        }
        part += __shfl_xor(part, 1, 64);
        part += __shfl_xor(part, 2, 64);
        part += __shfl_xor(part, 4, 64);
        part += __shfl_xor(part, 8, 64);
        if (l15 == 0) spart[w][rt*16 + l4*4 + r] = part;
      }
    }
  }
  __syncthreads();
  if (t < 64) {
    int p = rowbase + t;
    float raw = spart[0][t] + spart[1][t] + spart[2][t] + spart[3][t] + b3[0];
    scores[p] = (sDist[t] <= CUTF) ? raw : 0.0f;
  }
}

// ---------------- kernel 6: softmax + weighted V + coord update ----------------
__global__ void k_combine(const float* __restrict__ scores, const int* __restrict__ idx,
    const float* __restrict__ vf, const float* __restrict__ gates,
    const float4* __restrict__ cen4, const float* __restrict__ ef,
    const float* __restrict__ ec, float* __restrict__ upd, float* __restrict__ outc) {
  int e = blockIdx.x, t = threadIdx.x;   // 128 threads
  __shared__ float wk[KNB];
  __shared__ float sd[3][KNB];
  __shared__ int jj[KNB];
  if (t < 64) {
    float sc = (t < KNB) ? scores[e*KNB + t] : -1e30f;
    float m = sc;
    #pragma unroll
    for (int mm = 1; mm < 32; mm <<= 1) m = fmaxf(m, __shfl_xor(m, mm, 64));
    m = fmaxf(m, 0.0f);
    float ex = (t < KNB) ? __expf(sc - m) : 0.0f;
    float Z = ex;
    #pragma unroll
    for (int mm = 1; mm < 32; mm <<= 1) Z += __shfl_xor(Z, mm, 64);
    Z += 8160.0f * __expf(-m);             // (E-K) zero-score tail
    if (t < KNB) {
      float wv = ex / Z;
      int j = idx[e*KNB + t];
      jj[t] = j; wk[t] = wv;
      float g = wv * gates[j];
      float4 ce = cen4[e], cj = cen4[j];
      sd[0][t] = g*(ce.x - cj.x);
      sd[1][t] = g*(ce.y - cj.y);
      sd[2][t] = g*(ce.z - cj.z);
    }
  }
  __syncthreads();
  float acc = 0.0f;
  #pragma unroll 4
  for (int kk = 0; kk < KNB; ++kk) acc = fmaf(wk[kk], vf[(size_t)jj[kk]*HID + t], acc);
  upd[e*HID + t] = ef[e*HID + t] + acc;
  if (t < 3) {
    float csum = 0.0f;
    #pragma unroll 4
    for (int kk = 0; kk < KNB; ++kk) csum += sd[t][kk];
    outc[e*3 + t] = ec[e*3 + t] + csum;
  }
}

// ---------------- kernel 7: output projection + residual + LayerNorm, 8 edges/block ----------------
__global__ __launch_bounds__(256) void k_out(const float* __restrict__ upd,
    const float* __restrict__ ef,
    const float* __restrict__ Wo, const float* __restrict__ bo,
    const float* __restrict__ gamma, const float* __restrict__ beta,
    float* __restrict__ outf) {
  const int t = threadIdx.x;
  const int e0 = blockIdx.x * 8;
  const int o = t & 127, h = t >> 7;
  __shared__ float us[8][128];
  __shared__ float xs[8][128];
  #pragma unroll
  for (int i = 0; i < 4; ++i) {
    int ii = t + i*256;
    us[ii >> 7][ii & 127] = upd[e0*HID + ii];
  }
  __syncthreads();
  float acc[4] = {0,0,0,0};
  #pragma unroll 4
  for (int d = 0; d < 128; ++d) {
    float wo = Wo[d*128+o];
    #pragma unroll
    for (int i = 0; i < 4; ++i) acc[i] = fmaf(us[h*4+i][d], wo, acc[i]);
  }
  float bb = bo[o];
  #pragma unroll
  for (int i = 0; i < 4; ++i) {
    int e = h*4+i;
    xs[e][o] = ef[(e0+e)*HID + o] + acc[i] + bb;
  }
  __syncthreads();
  const int w = t >> 6, lane = t & 63;
  #pragma unroll
  for (int ii = 0; ii < 2; ++ii) {
    int e = w*2 + ii;
    float a = xs[e][lane], b = xs[e][64+lane];
    float s1 = a + b, s2 = a*a + b*b;
    #pragma unroll
    for (int m = 1; m < 64; m <<= 1) {
      s1 += __shfl_xor(s1, m, 64);
      s2 += __shfl_xor(s2, m, 64);
    }
    float mu = s1 * (1.0f/128.0f);
    float var = s2 * (1.0f/128.0f) - mu*mu;
    float rs = rsqrtf(var + LNEPS);
    outf[(e0+e)*HID + lane]      = (a - mu)*rs*gamma[lane]      + beta[lane];
    outf[(e0+e)*HID + 64 + lane] = (b - mu)*rs*gamma[64+lane]   + beta[64+lane];
  }
}

extern "C" void kernel_launch(void* const* d_in, const int* in_sizes, int n_in,
                              void* d_out, int out_size, void* d_ws, size_t ws_size,
                              hipStream_t stream) {
  const float* ef   = (const float*)d_in[0];
  const float* ec   = (const float*)d_in[1];
  const float* nc   = (const float*)d_in[2];
  const float* Wq   = (const float*)d_in[3];
  const float* Wk   = (const float*)d_in[4];
  const float* Wv   = (const float*)d_in[5];
  const float* W1   = (const float*)d_in[6];
  const float* b1   = (const float*)d_in[7];
  const float* W2   = (const float*)d_in[8];
  const float* b2   = (const float*)d_in[9];
  const float* W3   = (const float*)d_in[10];
  const float* b3   = (const float*)d_in[11];
  const float* Wg1  = (const float*)d_in[12];
  const float* bg1  = (const float*)d_in[13];
  const float* Wg2  = (const float*)d_in[14];
  const float* bg2  = (const float*)d_in[15];
  const float* Wo   = (const float*)d_in[16];
  const float* bo   = (const float*)d_in[17];
  const float* gamma= (const float*)d_in[18];
  const float* beta = (const float*)d_in[19];
  const float* centers = (const float*)d_in[20];
  const float* widths  = (const float*)d_in[21];
  const int*   eidx    = (const int*)d_in[22];

  float* outf = (float*)d_out;
  float* outc = outf + (size_t)E_N * HID;

  // workspace layout (16B-aligned chunks first)
  float4* cen4 = (float4*)d_ws;                        // 8192 * 16B
  u16*   Wt1r  = (u16*)(cen4 + E_N);                   // 128*64 bf16
  u16*   Wt2   = Wt1r + 128*64;                        // 128*128 bf16
  int*   idx   = (int*)(Wt2 + 128*128);
  float* qf    = (float*)(idx + E_N*KNB);
  float* kf    = qf + (size_t)E_N*HID;
  float* vf    = kf + (size_t)E_N*HID;
  float* qW1   = vf + (size_t)E_N*HID;
  float* kW1   = qW1 + (size_t)E_N*HID;
  float* scores= kW1 + (size_t)E_N*HID;
  float* gates = scores + E_N*KNB;
  float* upd   = gates + E_N;
  float* Wqc   = upd + (size_t)E_N*HID;                // 128*128 f32
  float* Wkc   = Wqc + 128*128;                        // 128*128 f32

  k_convw<<<128, 192, 0, stream>>>(W1, W2, Wt1r, Wt2);
  k_fusew<<<128, 128, 0, stream>>>(Wq, Wk, W1, Wqc, Wkc);
  k_prep<<<E_N/256, 256, 0, stream>>>(nc, eidx, cen4);
  k_topk<<<E_N, 256, 0, stream>>>(cen4, idx);
  k_qkv<<<E_N/8, 128, 0, stream>>>(ef, Wq, Wk, Wv, Wqc, Wkc, b1, Wg1, bg1, Wg2, bg2,
                                   qf, kf, vf, qW1, kW1, gates);
  k_mlp<<<E_N*KNB/64, 256, 0, stream>>>(idx, qf, kf, cen4, qW1, kW1, Wt1r, Wt2,
                                        W1, b2, W3, b3, centers, widths, scores);
  k_combine<<<E_N, 128, 0, stream>>>(scores, idx, vf, gates, cen4, ef, ec, upd, outc);
  k_out<<<E_N/8, 256, 0, stream>>>(upd, ef, Wo, bo, gamma, beta, outf);
}

// Round 8
// 276.151 us; speedup vs baseline: 1.0574x; 1.0574x over previous
//
#include <hip/hip_runtime.h>
#include <math.h>

#define E_N   8192
#define HID   128
#define NRAD  64
#define KNB   32
#define CUTF  10.0f
#define LNEPS 1e-5f

typedef unsigned short u16;
typedef unsigned int   u32;
typedef unsigned long long u64;
typedef __bf16 bf16x8 __attribute__((ext_vector_type(8)));
typedef u16    u16x8  __attribute__((ext_vector_type(8)));
typedef float  f32x4  __attribute__((ext_vector_type(4)));

__device__ __forceinline__ u16 f2bf(float f) {
  unsigned u = __float_as_uint(f);
  unsigned r = (u + 0x7fffu + ((u >> 16) & 1u)) >> 16;   // RNE
  return (u16)r;
}

__device__ __forceinline__ u64 shflx64(u64 v, int m) {
  int lo = __shfl_xor((int)(v & 0xffffffffull), m, 64);
  int hi = __shfl_xor((int)(v >> 32), m, 64);
  return ((u64)(unsigned)hi << 32) | (unsigned)lo;
}

// ---------------- kernel 0a: bf16 weight prep (rbf block of W1, W2), transposed ----------------
__global__ void k_convw(const float* __restrict__ W1, const float* __restrict__ W2,
                        u16* __restrict__ Wt1r, u16* __restrict__ Wt2) {
  int b = blockIdx.x;            // output col 0..127
  int t = threadIdx.x;           // 0..191
  if (t < 64)       Wt1r[b*64 + t]        = f2bf(W1[(256+t)*HID + b]);   // rbf rows 256..319
  else if (t < 192) Wt2[b*HID + (t-64)]   = f2bf(W2[(t-64)*HID + b]);
}

// ---------------- kernel 0b: fused weight products Wqc = Wq@W1[0:128], Wkc = Wk@W1[128:256] ----------------
__global__ void k_fusew(const float* __restrict__ Wq, const float* __restrict__ Wk,
                        const float* __restrict__ W1,
                        float* __restrict__ Wqc, float* __restrict__ Wkc) {
  int r = blockIdx.x, o = threadIdx.x;   // 128 x 128
  float a = 0.f, b = 0.f;
  #pragma unroll 8
  for (int m = 0; m < 128; ++m) {
    a = fmaf(Wq[r*128+m], W1[m*128+o], a);
    b = fmaf(Wk[r*128+m], W1[(128+m)*128+o], b);
  }
  Wqc[r*128+o] = a; Wkc[r*128+o] = b;
}

// ---------------- kernel 1: edge centers + squared norms (packed float4) ----------------
__global__ void k_prep(const float* __restrict__ nc, const int* __restrict__ ei,
                       float4* __restrict__ cen4) {
  int e = blockIdx.x * 256 + threadIdx.x;
  if (e >= E_N) return;
  int a = ei[e], b = ei[E_N + e];
  float x = (nc[a*3+0] + nc[b*3+0]) * 0.5f;
  float y = (nc[a*3+1] + nc[b*3+1]) * 0.5f;
  float z = (nc[a*3+2] + nc[b*3+2]) * 0.5f;
  cen4[e] = make_float4(x, y, z, x*x + y*y + z*z);
}

// ---------------- kernel 2: top-K via bitonic min-rank bound + exact lex rank ----------------
// 1 row/block, 256 threads, keys in 32 VGPRs. U = exact 32nd-smallest of the
// 256 per-thread mins, computed with register-only bitonic sorts:
//   (a) each wave sorts its 64 mins across lanes (21 shfl stages, no barrier);
//   (b) each wave's sorted 32-prefix -> LDS (rank-31 of 256 must lie in some
//       wave's first 32); 1 barrier;
//   (c) wave 0 bitonic-sorts the 128 prefix values (2 regs/lane, 28 stages);
//       sorted position 31 = exact 32nd-smallest; 1 barrier to broadcast.
// Bound proof: <=31 keys < T  =>  <=31 thread-mins < T  =>  U >= T. Survivors
// (key <= U) contain the exact top-32; exact (key,idx) lex rank matches
// jax.lax.top_k tie order. Fallback guards the never-case overflow.
__global__ __launch_bounds__(256) void k_topk(const float4* __restrict__ cen4,
                                              int* __restrict__ idxo) {
  const int row = blockIdx.x;
  const int t = threadIdx.x;
  const int lane = t & 63, w = t >> 6;
  __shared__ u32 pref[4][32];
  __shared__ u32 sU, scnt;
  __shared__ __align__(16) u64 comp[2048];     // 16 KiB survivor buffer
  __shared__ u64 wred[4];
  __shared__ u64 winner;

  const float4 me = cen4[row];
  u32 keys[32];
  u32 mn = 0xFFFFFFFFu;
  #pragma unroll
  for (int s = 0; s < 32; ++s) {
    int j = t + (s << 8);
    float4 c = cen4[j];
    float dot = me.x*c.x + me.y*c.y + me.z*c.z;
    float d2 = (me.w + c.w) - 2.0f*dot;       // identical to reference gram trick
    unsigned u = __float_as_uint(d2);
    u = u ^ (((u32)((int)u >> 31)) | 0x80000000u);   // monotone map
    keys[s] = u; mn = u < mn ? u : mn;
  }
  if (t == 0) scnt = 0;

  // ---- (a) in-wave bitonic sort of the 64 per-thread mins (ascending) ----
  u32 v = mn;
  #pragma unroll
  for (int k = 2; k <= 64; k <<= 1) {
    #pragma unroll
    for (int j = k >> 1; j > 0; j >>= 1) {
      u32 o = (u32)__shfl_xor((int)v, j, 64);
      bool up = (lane & k) == 0;            // k=64: always true -> ascending
      bool lower = (lane & j) == 0;
      u32 lo = v < o ? v : o, hi = v < o ? o : v;
      v = (lower == up) ? lo : hi;
    }
  }
  if (lane < 32) pref[w][lane] = v;
  __syncthreads();

  // ---- (c) wave 0: sort the 128 prefix values; position 31 = exact bound ----
  if (w == 0) {
    u32 a = pref[lane >> 5][lane & 31];        // idx = lane
    u32 b = pref[2 + (lane >> 5)][lane & 31];  // idx = 64 + lane
    #pragma unroll
    for (int k = 2; k <= 64; k <<= 1) {
      #pragma unroll
      for (int j = k >> 1; j > 0; j >>= 1) {
        u32 oa = (u32)__shfl_xor((int)a, j, 64);
        u32 ob = (u32)__shfl_xor((int)b, j, 64);
        bool lower = (lane & j) == 0;
        bool upA = (k == 64) ? true  : ((lane & k) == 0);
        bool upB = (k == 64) ? false : upA;    // idx_b & 64 = 64 -> descending
        u32 loa = a < oa ? a : oa, hia = a < oa ? oa : a;
        u32 lob = b < ob ? b : ob, hib = b < ob ? ob : b;
        a = (lower == upA) ? loa : hia;
        b = (lower == upB) ? lob : hib;
      }
    }
    // final 128-merge (a asc, b desc form a bitonic sequence), all ascending
    { u32 lo = a < b ? a : b, hi = a < b ? b : a; a = lo; b = hi; }
    #pragma unroll
    for (int j = 32; j > 0; j >>= 1) {
      u32 oa = (u32)__shfl_xor((int)a, j, 64);
      u32 ob = (u32)__shfl_xor((int)b, j, 64);
      bool lower = (lane & j) == 0;
      u32 loa = a < oa ? a : oa, hia = a < oa ? oa : a;
      u32 lob = b < ob ? b : ob, hib = b < ob ? ob : b;
      a = lower ? loa : hia;
      b = lower ? lob : hib;
    }
    if (lane == 31) sU = a;                    // sorted position 31
  }
  __syncthreads();
  const u32 U = sU;

  // ---- compact survivors (key <= U) ----
  #pragma unroll
  for (int s = 0; s < 32; ++s) {
    if (keys[s] <= U) {
      u32 pos = atomicAdd(&scnt, 1u);
      if (pos < 2048u) comp[pos] = (((u64)keys[s]) << 13) | (u32)(t + (s << 8));
    }
  }
  __syncthreads();
  const int cnt = (int)scnt;      // block-uniform

  if (cnt <= 2048) {
    // exact lex ranking on survivors (vectorized u64-pair reads)
    for (int i = t; i < cnt; i += 256) {
      u64 mev = comp[i];
      int rk = 0;
      int j2 = 0;
      for (; j2 + 2 <= cnt; j2 += 2) {
        ulonglong2 pr = *(const ulonglong2*)&comp[j2];
        rk += (pr.x < mev) ? 1 : 0;
        rk += (pr.y < mev) ? 1 : 0;
      }
      if (j2 < cnt) rk += (comp[j2] < mev) ? 1 : 0;
      if (rk < KNB) idxo[row*KNB + rk] = (int)(mev & 0x1FFFull);
    }
  } else {
    // overflow fallback (correctness guard; statistically never taken):
    // 32 rounds of block-wide min extraction on packed (key, idx)
    u64 lk = 0xFFFFFFFFFFFFFFFFull;
    #pragma unroll
    for (int s = 0; s < 32; ++s) {
      u64 kk = (((u64)keys[s]) << 13) | (u32)(t + (s << 8));
      lk = kk < lk ? kk : lk;
    }
    for (int kk2 = 0; kk2 < KNB; ++kk2) {
      u64 r2 = lk;
      #pragma unroll
      for (int m = 1; m < 64; m <<= 1) {
        u64 o = shflx64(r2, m);
        r2 = o < r2 ? o : r2;
      }
      if (lane == 0) wred[w] = r2;
      __syncthreads();
      if (t == 0) {
        u64 w0 = wred[0] < wred[1] ? wred[0] : wred[1];
        u64 w1 = wred[2] < wred[3] ? wred[2] : wred[3];
        winner = w0 < w1 ? w0 : w1;
        idxo[row*KNB + kk2] = (int)(winner & 0x1FFFull);
      }
      __syncthreads();
      u64 jw = winner & 0x1FFFull;
      if (((u32)jw & 255u) == (u32)t) {
        keys[(int)(jw >> 8)] = 0xFFFFFFFFu;
        lk = 0xFFFFFFFFFFFFFFFFull;
        #pragma unroll
        for (int s = 0; s < 32; ++s) {
          u64 kx = (((u64)keys[s]) << 13) | (u32)(t + (s << 8));
          lk = kx < lk ? kx : lk;
        }
      }
      __syncthreads();
    }
  }
}

// ---------------- kernel 3: q,k,v + fused-projection rows + gates, 8 edges/block ----------------
__global__ __launch_bounds__(128) void k_qkv(const float* __restrict__ ef,
    const float* __restrict__ Wq, const float* __restrict__ Wk, const float* __restrict__ Wv,
    const float* __restrict__ Wqc, const float* __restrict__ Wkc, const float* __restrict__ b1,
    const float* __restrict__ Wg1, const float* __restrict__ bg1,
    const float* __restrict__ Wg2, const float* __restrict__ bg2,
    float* __restrict__ qf, float* __restrict__ kf, float* __restrict__ vf,
    float* __restrict__ qW1, float* __restrict__ kW1, float* __restrict__ gates) {
  const int o = threadIdx.x;
  const int e0 = blockIdx.x * 8;
  __shared__ float efs[8][128];
  __shared__ float vs[8][128];
  __shared__ float gred[8][2];

  #pragma unroll
  for (int e = 0; e < 8; ++e) efs[e][o] = ef[(e0+e)*HID + o];
  __syncthreads();

  float aq[8] = {0}, ak[8] = {0}, av[8] = {0}, aqc[8] = {0}, akc[8] = {0};
  #pragma unroll 4
  for (int d = 0; d < 128; ++d) {
    float wq = Wq[d*128+o], wk = Wk[d*128+o], wv = Wv[d*128+o];
    float wc1 = Wqc[d*128+o], wc2 = Wkc[d*128+o];
    #pragma unroll
    for (int e = 0; e < 8; ++e) {
      float a = efs[e][d];
      aq[e]  = fmaf(a, wq,  aq[e]);
      ak[e]  = fmaf(a, wk,  ak[e]);
      av[e]  = fmaf(a, wv,  av[e]);
      aqc[e] = fmaf(a, wc1, aqc[e]);
      akc[e] = fmaf(a, wc2, akc[e]);
    }
  }
  float bb1 = b1[o];
  #pragma unroll
  for (int e = 0; e < 8; ++e) {
    qf[(e0+e)*HID+o] = aq[e]; kf[(e0+e)*HID+o] = ak[e]; vf[(e0+e)*HID+o] = av[e];
    qW1[(e0+e)*HID+o] = aqc[e] + bb1;
    kW1[(e0+e)*HID+o] = akc[e];
    vs[e][o] = av[e];
  }
  __syncthreads();

  float ag[8] = {0};
  #pragma unroll 4
  for (int d = 0; d < 128; ++d) {
    float wg = Wg1[d*128+o];
    #pragma unroll
    for (int e = 0; e < 8; ++e) ag[e] = fmaf(vs[e][d], wg, ag[e]);
  }
  float bgo = bg1[o], w2 = Wg2[o];
  const int lane = o & 63, w = o >> 6;
  #pragma unroll
  for (int e = 0; e < 8; ++e) {
    float g = ag[e] + bgo;
    g = g / (1.0f + __expf(-g));
    float part = g * w2;
    #pragma unroll
    for (int m = 1; m < 64; m <<= 1) part += __shfl_xor(part, m, 64);
    if (lane == 0) gred[e][w] = part;
  }
  __syncthreads();
  if (o < 8) gates[e0+o] = 1.0f / (1.0f + __expf(-(gred[o][0] + gred[o][1] + bg2[0])));
}

// ---------------- kernel 5: fused attention MLP -> scores (bf16 MFMA, geom folded in) ----------------
__global__ __launch_bounds__(256) void k_mlp(
    const int* __restrict__ idx,
    const float* __restrict__ qf, const float* __restrict__ kf,
    const float4* __restrict__ cen4,
    const float* __restrict__ qW1, const float* __restrict__ kW1,
    const u16* __restrict__ Wt1r, const u16* __restrict__ Wt2,
    const float* __restrict__ W1,           // for w320 row
    const float* __restrict__ b2, const float* __restrict__ W3,
    const float* __restrict__ b3,
    const float* __restrict__ centers, const float* __restrict__ widths,
    float* __restrict__ scores) {
  __shared__ u16 sA[64*64];       // rbf tile, swizzled (8 KiB)
  __shared__ u16 sH[64*128];      // h tile, swizzled (16 KiB)
  __shared__ float spart[4][64];
  __shared__ float sQW[2][128];
  __shared__ float sDot[64];
  __shared__ float sDist[64];
  __shared__ int   sIdx[64];

  const int t  = threadIdx.x;
  const int w  = t >> 6, l = t & 63;
  const int l15 = l & 15, l4 = l >> 4;
  const int rowbase = blockIdx.x * 64;
  const int eBase = rowbase >> 5;           // two edges per block

  // ---- stage: dot + dist + rbf tile + per-edge qW1 rows ----
  const int srow = t >> 2, sb = t & 3;
  const int sp = rowbase + srow;
  const int se = sp >> 5;
  const int sj = idx[sp];
  // q.k dot (4 threads per row, 32 MACs each)
  const float4* q4 = (const float4*)(qf + (size_t)se*HID) + sb*8;
  const float4* k4 = (const float4*)(kf + (size_t)sj*HID) + sb*8;
  float dt = 0.f;
  #pragma unroll
  for (int i = 0; i < 8; ++i) {
    float4 a = q4[i], b = k4[i];
    dt += a.x*b.x + a.y*b.y + a.z*b.z + a.w*b.w;
  }
  dt += __shfl_xor(dt, 1, 64);
  dt += __shfl_xor(dt, 2, 64);
  // geometry
  float4 ce = cen4[se], cj = cen4[sj];
  float ddx = ce.x - cj.x, ddy = ce.y - cj.y, ddz = ce.z - cj.z;
  const float sdist = sqrtf(ddx*ddx + ddy*ddy + ddz*ddz);
  const float sincut = (sdist <= CUTF) ? 1.0f : 0.0f;
  if (sb == 0) { sDot[srow] = dt; sDist[srow] = sdist; }
  {
    u16 tmp[16];
    #pragma unroll
    for (int i4 = 0; i4 < 4; ++i4) {
      float4 cc = *(const float4*)(centers + sb*16 + i4*4);
      float4 ww = *(const float4*)(widths  + sb*16 + i4*4);
      float c4[4] = {cc.x,cc.y,cc.z,cc.w}, w4[4] = {ww.x,ww.y,ww.z,ww.w};
      #pragma unroll
      for (int jj = 0; jj < 4; ++jj) {
        float df = sdist - c4[jj];
        tmp[i4*4+jj] = f2bf(__expf(-w4[jj]*df*df) * sincut);
      }
    }
    #pragma unroll
    for (int g = 0; g < 2; ++g) {
      u16x8 vv;
      #pragma unroll
      for (int jj = 0; jj < 8; ++jj) vv[jj] = tmp[g*8+jj];
      int widx = (srow*64 + sb*16 + g*8) ^ ((srow & 7) << 3);
      *(u16x8*)(&sA[widx]) = vv;
    }
  }
  sQW[t >> 7][t & 127] = qW1[(size_t)(eBase + (t >> 7))*HID + (t & 127)];
  if (t < 64) sIdx[t] = idx[rowbase + t];
  __syncthreads();

  f32x4 acc[4][2];
  #pragma unroll
  for (int rt = 0; rt < 4; ++rt)
    #pragma unroll
    for (int ct = 0; ct < 2; ++ct) acc[rt][ct] = (f32x4){0.f,0.f,0.f,0.f};

  // ---- GEMM1: rbf (K=64) ----
  #pragma unroll
  for (int ks = 0; ks < 2; ++ks) {
    bf16x8 af[4], bfr[2];
    #pragma unroll
    for (int rt = 0; rt < 4; ++rt) {
      int row = rt*16 + l15;
      int aidx = (row*64 + ks*32 + l4*8) ^ ((row & 7) << 3);
      af[rt] = *(const bf16x8*)(&sA[aidx]);
    }
    #pragma unroll
    for (int ct = 0; ct < 2; ++ct) {
      int col = w*32 + ct*16 + l15;
      bfr[ct] = *(const bf16x8*)(&Wt1r[col*64 + ks*32 + l4*8]);
    }
    #pragma unroll
    for (int rt = 0; rt < 4; ++rt)
      #pragma unroll
      for (int ct = 0; ct < 2; ++ct)
        acc[rt][ct] = __builtin_amdgcn_mfma_f32_16x16x32_bf16(af[rt], bfr[ct], acc[rt][ct], 0, 0, 0);
  }

  // ---- epilogue 1: + qW1[e] + kW1[j] + dot*w320, silu -> sH bf16 (swizzled) ----
  {
    float w320[2];
    #pragma unroll
    for (int ct = 0; ct < 2; ++ct) {
      int col = w*32 + ct*16 + l15;
      w320[ct] = W1[320*HID + col];
    }
    #pragma unroll
    for (int rt = 0; rt < 4; ++rt) {
      #pragma unroll
      for (int r = 0; r < 4; ++r) {
        int row = rt*16 + l4*4 + r;
        float dv = sDot[row];
        int jrow = sIdx[row];
        int eh = row >> 5;
        #pragma unroll
        for (int ct = 0; ct < 2; ++ct) {
          int col = w*32 + ct*16 + l15;
          float x = acc[rt][ct][r] + sQW[eh][col] + kW1[(size_t)jrow*HID + col] + dv*w320[ct];
          float h = x / (1.0f + __expf(-x));
          sH[(row*128 + col) ^ ((row & 7) << 3)] = f2bf(h);
        }
      }
    }
  }
  __syncthreads();

  #pragma unroll
  for (int rt = 0; rt < 4; ++rt)
    #pragma unroll
    for (int ct = 0; ct < 2; ++ct) acc[rt][ct] = (f32x4){0.f,0.f,0.f,0.f};

  // ---- GEMM2: h @ W2 ----
  #pragma unroll
  for (int ks = 0; ks < 4; ++ks) {
    bf16x8 af[4], bfr[2];
    #pragma unroll
    for (int rt = 0; rt < 4; ++rt) {
      int row = rt*16 + l15;
      int aidx = (row*128 + ks*32 + l4*8) ^ ((row & 7) << 3);
      af[rt] = *(const bf16x8*)(&sH[aidx]);
    }
    #pragma unroll
    for (int ct = 0; ct < 2; ++ct) {
      int col = w*32 + ct*16 + l15;
      bfr[ct] = *(const bf16x8*)(&Wt2[col*128 + ks*32 + l4*8]);
    }
    #pragma unroll
    for (int rt = 0; rt < 4; ++rt)
      #pragma unroll
      for (int ct = 0; ct < 2; ++ct)
        acc[rt][ct] = __builtin_amdgcn_mfma_f32_16x16x32_bf16(af[rt], bfr[ct], acc[rt][ct], 0, 0, 0);
  }

  // ---- epilogue 2: silu, dot W3, reduce ----
  {
    float b2r[2], w3r[2];
    #pragma unroll
    for (int ct = 0; ct < 2; ++ct) {
      int col = w*32 + ct*16 + l15;
      b2r[ct] = b2[col]; w3r[ct] = W3[col];
    }
    #pragma unroll
    for (int rt = 0; rt < 4; ++rt) {
      #pragma unroll
      for (int r = 0; r < 4; ++r) {
        float part = 0.f;
        #pragma unroll
        for (int ct = 0; ct < 2; ++ct) {
          float x = acc[rt][ct][r] + b2r[ct];
          float h = x / (1.0f + __expf(-x));
          part = fmaf(h, w3r[ct], part);
        }
        part += __shfl_xor(part, 1, 64);
        part += __shfl_xor(part, 2, 64);
        part += __shfl_xor(part, 4, 64);
        part += __shfl_xor(part, 8, 64);
        if (l15 == 0) spart[w][rt*16 + l4*4 + r] = part;
      }
    }
  }
  __syncthreads();
  if (t < 64) {
    int p = rowbase + t;
    float raw = spart[0][t] + spart[1][t] + spart[2][t] + spart[3][t] + b3[0];
    scores[p] = (sDist[t] <= CUTF) ? raw : 0.0f;
  }
}

// ---------------- kernel 6: softmax + weighted V + coord update ----------------
__global__ void k_combine(const float* __restrict__ scores, const int* __restrict__ idx,
    const float* __restrict__ vf, const float* __restrict__ gates,
    const float4* __restrict__ cen4, const float* __restrict__ ef,
    const float* __restrict__ ec, float* __restrict__ upd, float* __restrict__ outc) {
  int e = blockIdx.x, t = threadIdx.x;   // 128 threads
  __shared__ float wk[KNB];
  __shared__ float sd[3][KNB];
  __shared__ int jj[KNB];
  if (t < 64) {
    float sc = (t < KNB) ? scores[e*KNB + t] : -1e30f;
    float m = sc;
    #pragma unroll
    for (int mm = 1; mm < 32; mm <<= 1) m = fmaxf(m, __shfl_xor(m, mm, 64));
    m = fmaxf(m, 0.0f);
    float ex = (t < KNB) ? __expf(sc - m) : 0.0f;
    float Z = ex;
    #pragma unroll
    for (int mm = 1; mm < 32; mm <<= 1) Z += __shfl_xor(Z, mm, 64);
    Z += 8160.0f * __expf(-m);             // (E-K) zero-score tail
    if (t < KNB) {
      float wv = ex / Z;
      int j = idx[e*KNB + t];
      jj[t] = j; wk[t] = wv;
      float g = wv * gates[j];
      float4 ce = cen4[e], cj = cen4[j];
      sd[0][t] = g*(ce.x - cj.x);
      sd[1][t] = g*(ce.y - cj.y);
      sd[2][t] = g*(ce.z - cj.z);
    }
  }
  __syncthreads();
  float acc = 0.0f;
  #pragma unroll 4
  for (int kk = 0; kk < KNB; ++kk) acc = fmaf(wk[kk], vf[(size_t)jj[kk]*HID + t], acc);
  upd[e*HID + t] = ef[e*HID + t] + acc;
  if (t < 3) {
    float csum = 0.0f;
    #pragma unroll 4
    for (int kk = 0; kk < KNB; ++kk) csum += sd[t][kk];
    outc[e*3 + t] = ec[e*3 + t] + csum;
  }
}

// ---------------- kernel 7: output projection + residual + LayerNorm, 8 edges/block ----------------
__global__ __launch_bounds__(256) void k_out(const float* __restrict__ upd,
    const float* __restrict__ ef,
    const float* __restrict__ Wo, const float* __restrict__ bo,
    const float* __restrict__ gamma, const float* __restrict__ beta,
    float* __restrict__ outf) {
  const int t = threadIdx.x;
  const int e0 = blockIdx.x * 8;
  const int o = t & 127, h = t >> 7;
  __shared__ float us[8][128];
  __shared__ float xs[8][128];
  #pragma unroll
  for (int i = 0; i < 4; ++i) {
    int ii = t + i*256;
    us[ii >> 7][ii & 127] = upd[e0*HID + ii];
  }
  __syncthreads();
  float acc[4] = {0,0,0,0};
  #pragma unroll 4
  for (int d = 0; d < 128; ++d) {
    float wo = Wo[d*128+o];
    #pragma unroll
    for (int i = 0; i < 4; ++i) acc[i] = fmaf(us[h*4+i][d], wo, acc[i]);
  }
  float bb = bo[o];
  #pragma unroll
  for (int i = 0; i < 4; ++i) {
    int e = h*4+i;
    xs[e][o] = ef[(e0+e)*HID + o] + acc[i] + bb;
  }
  __syncthreads();
  const int w = t >> 6, lane = t & 63;
  #pragma unroll
  for (int ii = 0; ii < 2; ++ii) {
    int e = w*2 + ii;
    float a = xs[e][lane], b = xs[e][64+lane];
    float s1 = a + b, s2 = a*a + b*b;
    #pragma unroll
    for (int m = 1; m < 64; m <<= 1) {
      s1 += __shfl_xor(s1, m, 64);
      s2 += __shfl_xor(s2, m, 64);
    }
    float mu = s1 * (1.0f/128.0f);
    float var = s2 * (1.0f/128.0f) - mu*mu;
    float rs = rsqrtf(var + LNEPS);
    outf[(e0+e)*HID + lane]      = (a - mu)*rs*gamma[lane]      + beta[lane];
    outf[(e0+e)*HID + 64 + lane] = (b - mu)*rs*gamma[64+lane]   + beta[64+lane];
  }
}

extern "C" void kernel_launch(void* const* d_in, const int* in_sizes, int n_in,
                              void* d_out, int out_size, void* d_ws, size_t ws_size,
                              hipStream_t stream) {
  const float* ef   = (const float*)d_in[0];
  const float* ec   = (const float*)d_in[1];
  const float* nc   = (const float*)d_in[2];
  const float* Wq   = (const float*)d_in[3];
  const float* Wk   = (const float*)d_in[4];
  const float* Wv   = (const float*)d_in[5];
  const float* W1   = (const float*)d_in[6];
  const float* b1   = (const float*)d_in[7];
  const float* W2   = (const float*)d_in[8];
  const float* b2   = (const float*)d_in[9];
  const float* W3   = (const float*)d_in[10];
  const float* b3   = (const float*)d_in[11];
  const float* Wg1  = (const float*)d_in[12];
  const float* bg1  = (const float*)d_in[13];
  const float* Wg2  = (const float*)d_in[14];
  const float* bg2  = (const float*)d_in[15];
  const float* Wo   = (const float*)d_in[16];
  const float* bo   = (const float*)d_in[17];
  const float* gamma= (const float*)d_in[18];
  const float* beta = (const float*)d_in[19];
  const float* centers = (const float*)d_in[20];
  const float* widths  = (const float*)d_in[21];
  const int*   eidx    = (const int*)d_in[22];

  float* outf = (float*)d_out;
  float* outc = outf + (size_t)E_N * HID;

  // workspace layout (16B-aligned chunks first)
  float4* cen4 = (float4*)d_ws;                        // 8192 * 16B
  u16*   Wt1r  = (u16*)(cen4 + E_N);                   // 128*64 bf16
  u16*   Wt2   = Wt1r + 128*64;                        // 128*128 bf16
  int*   idx   = (int*)(Wt2 + 128*128);
  float* qf    = (float*)(idx + E_N*KNB);
  float* kf    = qf + (size_t)E_N*HID;
  float* vf    = kf + (size_t)E_N*HID;
  float* qW1   = vf + (size_t)E_N*HID;
  float* kW1   = qW1 + (size_t)E_N*HID;
  float* scores= kW1 + (size_t)E_N*HID;
  float* gates = scores + E_N*KNB;
  float* upd   = gates + E_N;
  float* Wqc   = upd + (size_t)E_N*HID;                // 128*128 f32
  float* Wkc   = Wqc + 128*128;                        // 128*128 f32

  k_convw<<<128, 192, 0, stream>>>(W1, W2, Wt1r, Wt2);
  k_fusew<<<128, 128, 0, stream>>>(Wq, Wk, W1, Wqc, Wkc);
  k_prep<<<E_N/256, 256, 0, stream>>>(nc, eidx, cen4);
  k_topk<<<E_N, 256, 0, stream>>>(cen4, idx);
  k_qkv<<<E_N/8, 128, 0, stream>>>(ef, Wq, Wk, Wv, Wqc, Wkc, b1, Wg1, bg1, Wg2, bg2,
                                   qf, kf, vf, qW1, kW1, gates);
  k_mlp<<<E_N*KNB/64, 256, 0, stream>>>(idx, qf, kf, cen4, qW1, kW1, Wt1r, Wt2,
                                        W1, b2, W3, b3, centers, widths, scores);
  k_combine<<<E_N, 128, 0, stream>>>(scores, idx, vf, gates, cen4, ef, ec, upd, outc);
  k_out<<<E_N/8, 256, 0, stream>>>(upd, ef, Wo, bo, gamma, beta, outf);
}

// Round 9
// 233.179 us; speedup vs baseline: 1.2523x; 1.1843x over previous
//
#include <hip/hip_runtime.h>
#include <math.h>

#define E_N   8192
#define HID   128
#define NRAD  64
#define KNB   32
#define CUTF  10.0f
#define LNEPS 1e-5f

typedef unsigned short u16;
typedef unsigned int   u32;
typedef unsigned long long u64;
typedef __bf16 bf16x8 __attribute__((ext_vector_type(8)));
typedef u16    u16x8  __attribute__((ext_vector_type(8)));
typedef float  f32x4  __attribute__((ext_vector_type(4)));

__device__ __forceinline__ u16 f2bf(float f) {
  unsigned u = __float_as_uint(f);
  unsigned r = (u + 0x7fffu + ((u >> 16) & 1u)) >> 16;   // RNE
  return (u16)r;
}

__device__ __forceinline__ u64 shflx64(u64 v, int m) {
  int lo = __shfl_xor((int)(v & 0xffffffffull), m, 64);
  int hi = __shfl_xor((int)(v >> 32), m, 64);
  return ((u64)(unsigned)hi << 32) | (unsigned)lo;
}

// monotone-u32 key of squared distance; fmaf-pinned so pass1/pass2 agree bitwise
__device__ __forceinline__ u32 d2key(const float4 me, const float4 c) {
  float dot = fmaf(me.x, c.x, fmaf(me.y, c.y, me.z * c.z));
  float d2  = fmaf(-2.0f, dot, me.w + c.w);     // gram trick, as in reference
  u32 u = __float_as_uint(d2);
  return u ^ (((u32)((int)u >> 31)) | 0x80000000u);
}

// ---------------- kernel 0a: bf16 weight prep (rbf block of W1, W2), transposed ----------------
__global__ void k_convw(const float* __restrict__ W1, const float* __restrict__ W2,
                        u16* __restrict__ Wt1r, u16* __restrict__ Wt2) {
  int b = blockIdx.x;            // output col 0..127
  int t = threadIdx.x;           // 0..191
  if (t < 64)       Wt1r[b*64 + t]        = f2bf(W1[(256+t)*HID + b]);   // rbf rows 256..319
  else if (t < 192) Wt2[b*HID + (t-64)]   = f2bf(W2[(t-64)*HID + b]);
}

// ---------------- kernel 0b: fused weight products Wqc = Wq@W1[0:128], Wkc = Wk@W1[128:256] ----------------
__global__ void k_fusew(const float* __restrict__ Wq, const float* __restrict__ Wk,
                        const float* __restrict__ W1,
                        float* __restrict__ Wqc, float* __restrict__ Wkc) {
  int r = blockIdx.x, o = threadIdx.x;   // 128 x 128
  float a = 0.f, b = 0.f;
  #pragma unroll 8
  for (int m = 0; m < 128; ++m) {
    a = fmaf(Wq[r*128+m], W1[m*128+o], a);
    b = fmaf(Wk[r*128+m], W1[(128+m)*128+o], b);
  }
  Wqc[r*128+o] = a; Wkc[r*128+o] = b;
}

// ---------------- kernel 1: edge centers + squared norms (packed float4) ----------------
__global__ void k_prep(const float* __restrict__ nc, const int* __restrict__ ei,
                       float4* __restrict__ cen4) {
  int e = blockIdx.x * 256 + threadIdx.x;
  if (e >= E_N) return;
  int a = ei[e], b = ei[E_N + e];
  float x = (nc[a*3+0] + nc[b*3+0]) * 0.5f;
  float y = (nc[a*3+1] + nc[b*3+1]) * 0.5f;
  float z = (nc[a*3+2] + nc[b*3+2]) * 0.5f;
  cen4[e] = make_float4(x, y, z, x*x + y*y + z*z);
}

// ---------------- kernel 2: top-K, 8 rows/block, two-pass prune + exact lex rank ----------------
// Pass 1: stream candidates once, keep 8 per-row running mins (no key array).
// Bound per row: U = (rank-31 of the 256 thread-mins, radix-bisected in-wave on
// bits 31..12) rounded up by 0xFFF. Proof: <=31 keys < T => <=31 mins < T =>
// rank-31 min >= T => U >= T. Pass 2: recompute keys (identical fmaf-pinned
// code), compact survivors (key <= U_r) tagged (row|key|idx); exact lex rank
// gives jax.lax.top_k order (key asc, idx asc). Fallback guards overflow.
__global__ __launch_bounds__(256) void k_topk(const float4* __restrict__ cen4,
                                              int* __restrict__ idxo) {
  const int row0 = blockIdx.x * 8;
  const int t = threadIdx.x;
  const int lane = t & 63, w = t >> 6;
  __shared__ __align__(16) u32 smin[8][256];   // 8 KiB
  __shared__ __align__(16) u64 comp[2048];     // 16 KiB survivor buffer
  __shared__ u32 sU[8];
  __shared__ u32 scnt, scnt_r[8];
  __shared__ u64 wred[4];
  __shared__ u64 winner;

  if (t == 0) scnt = 0;
  if (t < 8) scnt_r[t] = 0;

  float4 me[8];
  #pragma unroll
  for (int r = 0; r < 8; ++r) me[r] = cen4[row0 + r];

  // ---- pass 1: running mins for 8 rows ----
  u32 mn[8];
  #pragma unroll
  for (int r = 0; r < 8; ++r) mn[r] = 0xFFFFFFFFu;
  for (int s = 0; s < 32; ++s) {
    float4 c = cen4[t + (s << 8)];
    #pragma unroll
    for (int r = 0; r < 8; ++r) {
      u32 k = d2key(me[r], c);
      mn[r] = k < mn[r] ? k : mn[r];
    }
  }
  #pragma unroll
  for (int r = 0; r < 8; ++r) smin[r][t] = mn[r];
  __syncthreads();

  // ---- per-row bound: wave w handles rows 2w, 2w+1; in-wave radix bisect ----
  #pragma unroll
  for (int rr = 0; rr < 2; ++rr) {
    const int r = w*2 + rr;
    uint4 vv = *(const uint4*)&smin[r][lane*4];
    u32 P = 0;
    u32 rem = 31;
    #pragma unroll 1
    for (int b = 31; b >= 12; --b) {
      u32 bit = 1u << b;
      bool pm0 = ((u64)(vv.x ^ P) >> (b+1)) == 0ull;
      bool pm1 = ((u64)(vv.y ^ P) >> (b+1)) == 0ull;
      bool pm2 = ((u64)(vv.z ^ P) >> (b+1)) == 0ull;
      bool pm3 = ((u64)(vv.w ^ P) >> (b+1)) == 0ull;
      u32 c0 = (u32)__popcll(__ballot(pm0 && !(vv.x & bit)))
             + (u32)__popcll(__ballot(pm1 && !(vv.y & bit)))
             + (u32)__popcll(__ballot(pm2 && !(vv.z & bit)))
             + (u32)__popcll(__ballot(pm3 && !(vv.w & bit)));
      if (rem >= c0) { P |= bit; rem -= c0; }
    }
    if (lane == 0) sU[r] = P | 0xFFFu;
  }
  __syncthreads();

  // ---- pass 2: recompute keys, compact survivors ----
  u32 Ur[8];
  #pragma unroll
  for (int r = 0; r < 8; ++r) Ur[r] = sU[r];
  for (int s = 0; s < 32; ++s) {
    float4 c = cen4[t + (s << 8)];
    #pragma unroll
    for (int r = 0; r < 8; ++r) {
      u32 k = d2key(me[r], c);
      if (k <= Ur[r]) {
        u32 pos = atomicAdd(&scnt, 1u);
        atomicAdd(&scnt_r[r], 1u);
        if (pos < 2048u)
          comp[pos] = ((u64)r << 45) | (((u64)k) << 13) | (u32)(t + (s << 8));
      }
    }
  }
  __syncthreads();
  const int cnt = (int)scnt;

  if (cnt <= 2048) {
    // per-row exclusive offsets
    u32 off[8];
    off[0] = 0;
    #pragma unroll
    for (int r = 1; r < 8; ++r) off[r] = off[r-1] + scnt_r[r-1];
    // exact lex ranking
    for (int i = t; i < cnt; i += 256) {
      u64 mev = comp[i];
      int rk = 0;
      int j2 = 0;
      for (; j2 + 2 <= cnt; j2 += 2) {
        ulonglong2 pr = *(const ulonglong2*)&comp[j2];
        rk += (pr.x < mev) ? 1 : 0;
        rk += (pr.y < mev) ? 1 : 0;
      }
      if (j2 < cnt) rk += (comp[j2] < mev) ? 1 : 0;
      int r = (int)(mev >> 45);
      int rank = rk - (int)off[r];
      if (rank < KNB) idxo[(row0 + r)*KNB + rank] = (int)(mev & 0x1FFFull);
    }
  } else {
    // overflow fallback (never taken statistically): exact per-row extract-min,
    // keys recomputed on the fly (no register key array)
    for (int r = 0; r < 8; ++r) {
      float4 mer = cen4[row0 + r];
      u32 taken = 0;
      for (int kk2 = 0; kk2 < KNB; ++kk2) {
        u64 lk = 0xFFFFFFFFFFFFFFFFull;
        for (int s = 0; s < 32; ++s) {
          if (taken & (1u << s)) continue;
          float4 c = cen4[t + (s << 8)];
          u64 kx = (((u64)d2key(mer, c)) << 13) | (u32)(t + (s << 8));
          lk = kx < lk ? kx : lk;
        }
        #pragma unroll
        for (int m = 1; m < 64; m <<= 1) {
          u64 o = shflx64(lk, m);
          lk = o < lk ? o : lk;
        }
        if (lane == 0) wred[w] = lk;
        __syncthreads();
        if (t == 0) {
          u64 w0 = wred[0] < wred[1] ? wred[0] : wred[1];
          u64 w1 = wred[2] < wred[3] ? wred[2] : wred[3];
          winner = w0 < w1 ? w0 : w1;
          idxo[(row0 + r)*KNB + kk2] = (int)(winner & 0x1FFFull);
        }
        __syncthreads();
        u64 jw = winner & 0x1FFFull;
        if (((u32)jw & 255u) == (u32)t) taken |= 1u << ((u32)jw >> 8);
        __syncthreads();
      }
    }
  }
}

// ---------------- kernel 3: q,k,v + fused-projection rows + gates, 8 edges/block ----------------
__global__ __launch_bounds__(128) void k_qkv(const float* __restrict__ ef,
    const float* __restrict__ Wq, const float* __restrict__ Wk, const float* __restrict__ Wv,
    const float* __restrict__ Wqc, const float* __restrict__ Wkc, const float* __restrict__ b1,
    const float* __restrict__ Wg1, const float* __restrict__ bg1,
    const float* __restrict__ Wg2, const float* __restrict__ bg2,
    float* __restrict__ qf, float* __restrict__ kf, float* __restrict__ vf,
    float* __restrict__ qW1, float* __restrict__ kW1, float* __restrict__ gates) {
  const int o = threadIdx.x;
  const int e0 = blockIdx.x * 8;
  __shared__ float efs[8][128];
  __shared__ float vs[8][128];
  __shared__ float gred[8][2];

  #pragma unroll
  for (int e = 0; e < 8; ++e) efs[e][o] = ef[(e0+e)*HID + o];
  __syncthreads();

  float aq[8] = {0}, ak[8] = {0}, av[8] = {0}, aqc[8] = {0}, akc[8] = {0};
  #pragma unroll 4
  for (int d = 0; d < 128; ++d) {
    float wq = Wq[d*128+o], wk = Wk[d*128+o], wv = Wv[d*128+o];
    float wc1 = Wqc[d*128+o], wc2 = Wkc[d*128+o];
    #pragma unroll
    for (int e = 0; e < 8; ++e) {
      float a = efs[e][d];
      aq[e]  = fmaf(a, wq,  aq[e]);
      ak[e]  = fmaf(a, wk,  ak[e]);
      av[e]  = fmaf(a, wv,  av[e]);
      aqc[e] = fmaf(a, wc1, aqc[e]);
      akc[e] = fmaf(a, wc2, akc[e]);
    }
  }
  float bb1 = b1[o];
  #pragma unroll
  for (int e = 0; e < 8; ++e) {
    qf[(e0+e)*HID+o] = aq[e]; kf[(e0+e)*HID+o] = ak[e]; vf[(e0+e)*HID+o] = av[e];
    qW1[(e0+e)*HID+o] = aqc[e] + bb1;
    kW1[(e0+e)*HID+o] = akc[e];
    vs[e][o] = av[e];
  }
  __syncthreads();

  float ag[8] = {0};
  #pragma unroll 4
  for (int d = 0; d < 128; ++d) {
    float wg = Wg1[d*128+o];
    #pragma unroll
    for (int e = 0; e < 8; ++e) ag[e] = fmaf(vs[e][d], wg, ag[e]);
  }
  float bgo = bg1[o], w2 = Wg2[o];
  const int lane = o & 63, w = o >> 6;
  #pragma unroll
  for (int e = 0; e < 8; ++e) {
    float g = ag[e] + bgo;
    g = g / (1.0f + __expf(-g));
    float part = g * w2;
    #pragma unroll
    for (int m = 1; m < 64; m <<= 1) part += __shfl_xor(part, m, 64);
    if (lane == 0) gred[e][w] = part;
  }
  __syncthreads();
  if (o < 8) gates[e0+o] = 1.0f / (1.0f + __expf(-(gred[o][0] + gred[o][1] + bg2[0])));
}

// ---------------- kernel 5: fused attention MLP -> scores (bf16 MFMA, geom folded in) ----------------
__global__ __launch_bounds__(256) void k_mlp(
    const int* __restrict__ idx,
    const float* __restrict__ qf, const float* __restrict__ kf,
    const float4* __restrict__ cen4,
    const float* __restrict__ qW1, const float* __restrict__ kW1,
    const u16* __restrict__ Wt1r, const u16* __restrict__ Wt2,
    const float* __restrict__ W1,           // for w320 row
    const float* __restrict__ b2, const float* __restrict__ W3,
    const float* __restrict__ b3,
    const float* __restrict__ centers, const float* __restrict__ widths,
    float* __restrict__ scores) {
  __shared__ u16 sA[64*64];       // rbf tile, swizzled (8 KiB)
  __shared__ u16 sH[64*128];      // h tile, swizzled (16 KiB)
  __shared__ float spart[4][64];
  __shared__ float sQW[2][128];
  __shared__ float sDot[64];
  __shared__ float sDist[64];
  __shared__ int   sIdx[64];

  const int t  = threadIdx.x;
  const int w  = t >> 6, l = t & 63;
  const int l15 = l & 15, l4 = l >> 4;
  const int rowbase = blockIdx.x * 64;
  const int eBase = rowbase >> 5;           // two edges per block

  // ---- stage: dot + dist + rbf tile + per-edge qW1 rows ----
  const int srow = t >> 2, sb = t & 3;
  const int sp = rowbase + srow;
  const int se = sp >> 5;
  const int sj = idx[sp];
  // q.k dot (4 threads per row, 32 MACs each)
  const float4* q4 = (const float4*)(qf + (size_t)se*HID) + sb*8;
  const float4* k4 = (const float4*)(kf + (size_t)sj*HID) + sb*8;
  float dt = 0.f;
  #pragma unroll
  for (int i = 0; i < 8; ++i) {
    float4 a = q4[i], b = k4[i];
    dt += a.x*b.x + a.y*b.y + a.z*b.z + a.w*b.w;
  }
  dt += __shfl_xor(dt, 1, 64);
  dt += __shfl_xor(dt, 2, 64);
  // geometry
  float4 ce = cen4[se], cj = cen4[sj];
  float ddx = ce.x - cj.x, ddy = ce.y - cj.y, ddz = ce.z - cj.z;
  const float sdist = sqrtf(ddx*ddx + ddy*ddy + ddz*ddz);
  const float sincut = (sdist <= CUTF) ? 1.0f : 0.0f;
  if (sb == 0) { sDot[srow] = dt; sDist[srow] = sdist; }
  {
    u16 tmp[16];
    #pragma unroll
    for (int i4 = 0; i4 < 4; ++i4) {
      float4 cc = *(const float4*)(centers + sb*16 + i4*4);
      float4 ww = *(const float4*)(widths  + sb*16 + i4*4);
      float c4[4] = {cc.x,cc.y,cc.z,cc.w}, w4[4] = {ww.x,ww.y,ww.z,ww.w};
      #pragma unroll
      for (int jj = 0; jj < 4; ++jj) {
        float df = sdist - c4[jj];
        tmp[i4*4+jj] = f2bf(__expf(-w4[jj]*df*df) * sincut);
      }
    }
    #pragma unroll
    for (int g = 0; g < 2; ++g) {
      u16x8 vv;
      #pragma unroll
      for (int jj = 0; jj < 8; ++jj) vv[jj] = tmp[g*8+jj];
      int widx = (srow*64 + sb*16 + g*8) ^ ((srow & 7) << 3);
      *(u16x8*)(&sA[widx]) = vv;
    }
  }
  sQW[t >> 7][t & 127] = qW1[(size_t)(eBase + (t >> 7))*HID + (t & 127)];
  if (t < 64) sIdx[t] = idx[rowbase + t];
  __syncthreads();

  f32x4 acc[4][2];
  #pragma unroll
  for (int rt = 0; rt < 4; ++rt)
    #pragma unroll
    for (int ct = 0; ct < 2; ++ct) acc[rt][ct] = (f32x4){0.f,0.f,0.f,0.f};

  // ---- GEMM1: rbf (K=64) ----
  #pragma unroll
  for (int ks = 0; ks < 2; ++ks) {
    bf16x8 af[4], bfr[2];
    #pragma unroll
    for (int rt = 0; rt < 4; ++rt) {
      int row = rt*16 + l15;
      int aidx = (row*64 + ks*32 + l4*8) ^ ((row & 7) << 3);
      af[rt] = *(const bf16x8*)(&sA[aidx]);
    }
    #pragma unroll
    for (int ct = 0; ct < 2; ++ct) {
      int col = w*32 + ct*16 + l15;
      bfr[ct] = *(const bf16x8*)(&Wt1r[col*64 + ks*32 + l4*8]);
    }
    #pragma unroll
    for (int rt = 0; rt < 4; ++rt)
      #pragma unroll
      for (int ct = 0; ct < 2; ++ct)
        acc[rt][ct] = __builtin_amdgcn_mfma_f32_16x16x32_bf16(af[rt], bfr[ct], acc[rt][ct], 0, 0, 0);
  }

  // ---- epilogue 1: + qW1[e] + kW1[j] + dot*w320, silu -> sH bf16 (swizzled) ----
  {
    float w320[2];
    #pragma unroll
    for (int ct = 0; ct < 2; ++ct) {
      int col = w*32 + ct*16 + l15;
      w320[ct] = W1[320*HID + col];
    }
    #pragma unroll
    for (int rt = 0; rt < 4; ++rt) {
      #pragma unroll
      for (int r = 0; r < 4; ++r) {
        int row = rt*16 + l4*4 + r;
        float dv = sDot[row];
        int jrow = sIdx[row];
        int eh = row >> 5;
        #pragma unroll
        for (int ct = 0; ct < 2; ++ct) {
          int col = w*32 + ct*16 + l15;
          float x = acc[rt][ct][r] + sQW[eh][col] + kW1[(size_t)jrow*HID + col] + dv*w320[ct];
          float h = x / (1.0f + __expf(-x));
          sH[(row*128 + col) ^ ((row & 7) << 3)] = f2bf(h);
        }
      }
    }
  }
  __syncthreads();

  #pragma unroll
  for (int rt = 0; rt < 4; ++rt)
    #pragma unroll
    for (int ct = 0; ct < 2; ++ct) acc[rt][ct] = (f32x4){0.f,0.f,0.f,0.f};

  // ---- GEMM2: h @ W2 ----
  #pragma unroll
  for (int ks = 0; ks < 4; ++ks) {
    bf16x8 af[4], bfr[2];
    #pragma unroll
    for (int rt = 0; rt < 4; ++rt) {
      int row = rt*16 + l15;
      int aidx = (row*128 + ks*32 + l4*8) ^ ((row & 7) << 3);
      af[rt] = *(const bf16x8*)(&sH[aidx]);
    }
    #pragma unroll
    for (int ct = 0; ct < 2; ++ct) {
      int col = w*32 + ct*16 + l15;
      bfr[ct] = *(const bf16x8*)(&Wt2[col*128 + ks*32 + l4*8]);
    }
    #pragma unroll
    for (int rt = 0; rt < 4; ++rt)
      #pragma unroll
      for (int ct = 0; ct < 2; ++ct)
        acc[rt][ct] = __builtin_amdgcn_mfma_f32_16x16x32_bf16(af[rt], bfr[ct], acc[rt][ct], 0, 0, 0);
  }

  // ---- epilogue 2: silu, dot W3, reduce ----
  {
    float b2r[2], w3r[2];
    #pragma unroll
    for (int ct = 0; ct < 2; ++ct) {
      int col = w*32 + ct*16 + l15;
      b2r[ct] = b2[col]; w3r[ct] = W3[col];
    }
    #pragma unroll
    for (int rt = 0; rt < 4; ++rt) {
      #pragma unroll
      for (int r = 0; r < 4; ++r) {
        float part = 0.f;
        #pragma unroll
        for (int ct = 0; ct < 2; ++ct) {
          float x = acc[rt][ct][r] + b2r[ct];
          float h = x / (1.0f + __expf(-x));
          part = fmaf(h, w3r[ct], part);
        }
        part += __shfl_xor(part, 1, 64);
        part += __shfl_xor(part, 2, 64);
        part += __shfl_xor(part, 4, 64);
        part += __shfl_xor(part, 8, 64);
        if (l15 == 0) spart[w][rt*16 + l4*4 + r] = part;
      }
    }
  }
  __syncthreads();
  if (t < 64) {
    int p = rowbase + t;
    float raw = spart[0][t] + spart[1][t] + spart[2][t] + spart[3][t] + b3[0];
    scores[p] = (sDist[t] <= CUTF) ? raw : 0.0f;
  }
}

// ---------------- kernel 6: softmax + weighted V + coord update ----------------
__global__ void k_combine(const float* __restrict__ scores, const int* __restrict__ idx,
    const float* __restrict__ vf, const float* __restrict__ gates,
    const float4* __restrict__ cen4, const float* __restrict__ ef,
    const float* __restrict__ ec, float* __restrict__ upd, float* __restrict__ outc) {
  int e = blockIdx.x, t = threadIdx.x;   // 128 threads
  __shared__ float wk[KNB];
  __shared__ float sd[3][KNB];
  __shared__ int jj[KNB];
  if (t < 64) {
    float sc = (t < KNB) ? scores[e*KNB + t] : -1e30f;
    float m = sc;
    #pragma unroll
    for (int mm = 1; mm < 32; mm <<= 1) m = fmaxf(m, __shfl_xor(m, mm, 64));
    m = fmaxf(m, 0.0f);
    float ex = (t < KNB) ? __expf(sc - m) : 0.0f;
    float Z = ex;
    #pragma unroll
    for (int mm = 1; mm < 32; mm <<= 1) Z += __shfl_xor(Z, mm, 64);
    Z += 8160.0f * __expf(-m);             // (E-K) zero-score tail
    if (t < KNB) {
      float wv = ex / Z;
      int j = idx[e*KNB + t];
      jj[t] = j; wk[t] = wv;
      float g = wv * gates[j];
      float4 ce = cen4[e], cj = cen4[j];
      sd[0][t] = g*(ce.x - cj.x);
      sd[1][t] = g*(ce.y - cj.y);
      sd[2][t] = g*(ce.z - cj.z);
    }
  }
  __syncthreads();
  float acc = 0.0f;
  #pragma unroll 4
  for (int kk = 0; kk < KNB; ++kk) acc = fmaf(wk[kk], vf[(size_t)jj[kk]*HID + t], acc);
  upd[e*HID + t] = ef[e*HID + t] + acc;
  if (t < 3) {
    float csum = 0.0f;
    #pragma unroll 4
    for (int kk = 0; kk < KNB; ++kk) csum += sd[t][kk];
    outc[e*3 + t] = ec[e*3 + t] + csum;
  }
}

// ---------------- kernel 7: output projection + residual + LayerNorm, 8 edges/block ----------------
__global__ __launch_bounds__(256) void k_out(const float* __restrict__ upd,
    const float* __restrict__ ef,
    const float* __restrict__ Wo, const float* __restrict__ bo,
    const float* __restrict__ gamma, const float* __restrict__ beta,
    float* __restrict__ outf) {
  const int t = threadIdx.x;
  const int e0 = blockIdx.x * 8;
  const int o = t & 127, h = t >> 7;
  __shared__ float us[8][128];
  __shared__ float xs[8][128];
  #pragma unroll
  for (int i = 0; i < 4; ++i) {
    int ii = t + i*256;
    us[ii >> 7][ii & 127] = upd[e0*HID + ii];
  }
  __syncthreads();
  float acc[4] = {0,0,0,0};
  #pragma unroll 4
  for (int d = 0; d < 128; ++d) {
    float wo = Wo[d*128+o];
    #pragma unroll
    for (int i = 0; i < 4; ++i) acc[i] = fmaf(us[h*4+i][d], wo, acc[i]);
  }
  float bb = bo[o];
  #pragma unroll
  for (int i = 0; i < 4; ++i) {
    int e = h*4+i;
    xs[e][o] = ef[(e0+e)*HID + o] + acc[i] + bb;
  }
  __syncthreads();
  const int w = t >> 6, lane = t & 63;
  #pragma unroll
  for (int ii = 0; ii < 2; ++ii) {
    int e = w*2 + ii;
    float a = xs[e][lane], b = xs[e][64+lane];
    float s1 = a + b, s2 = a*a + b*b;
    #pragma unroll
    for (int m = 1; m < 64; m <<= 1) {
      s1 += __shfl_xor(s1, m, 64);
      s2 += __shfl_xor(s2, m, 64);
    }
    float mu = s1 * (1.0f/128.0f);
    float var = s2 * (1.0f/128.0f) - mu*mu;
    float rs = rsqrtf(var + LNEPS);
    outf[(e0+e)*HID + lane]      = (a - mu)*rs*gamma[lane]      + beta[lane];
    outf[(e0+e)*HID + 64 + lane] = (b - mu)*rs*gamma[64+lane]   + beta[64+lane];
  }
}

extern "C" void kernel_launch(void* const* d_in, const int* in_sizes, int n_in,
                              void* d_out, int out_size, void* d_ws, size_t ws_size,
                              hipStream_t stream) {
  const float* ef   = (const float*)d_in[0];
  const float* ec   = (const float*)d_in[1];
  const float* nc   = (const float*)d_in[2];
  const float* Wq   = (const float*)d_in[3];
  const float* Wk   = (const float*)d_in[4];
  const float* Wv   = (const float*)d_in[5];
  const float* W1   = (const float*)d_in[6];
  const float* b1   = (const float*)d_in[7];
  const float* W2   = (const float*)d_in[8];
  const float* b2   = (const float*)d_in[9];
  const float* W3   = (const float*)d_in[10];
  const float* b3   = (const float*)d_in[11];
  const float* Wg1  = (const float*)d_in[12];
  const float* bg1  = (const float*)d_in[13];
  const float* Wg2  = (const float*)d_in[14];
  const float* bg2  = (const float*)d_in[15];
  const float* Wo   = (const float*)d_in[16];
  const float* bo   = (const float*)d_in[17];
  const float* gamma= (const float*)d_in[18];
  const float* beta = (const float*)d_in[19];
  const float* centers = (const float*)d_in[20];
  const float* widths  = (const float*)d_in[21];
  const int*   eidx    = (const int*)d_in[22];

  float* outf = (float*)d_out;
  float* outc = outf + (size_t)E_N * HID;

  // workspace layout (16B-aligned chunks first)
  float4* cen4 = (float4*)d_ws;                        // 8192 * 16B
  u16*   Wt1r  = (u16*)(cen4 + E_N);                   // 128*64 bf16
  u16*   Wt2   = Wt1r + 128*64;                        // 128*128 bf16
  int*   idx   = (int*)(Wt2 + 128*128);
  float* qf    = (float*)(idx + E_N*KNB);
  float* kf    = qf + (size_t)E_N*HID;
  float* vf    = kf + (size_t)E_N*HID;
  float* qW1   = vf + (size_t)E_N*HID;
  float* kW1   = qW1 + (size_t)E_N*HID;
  float* scores= kW1 + (size_t)E_N*HID;
  float* gates = scores + E_N*KNB;
  float* upd   = gates + E_N;
  float* Wqc   = upd + (size_t)E_N*HID;                // 128*128 f32
  float* Wkc   = Wqc + 128*128;                        // 128*128 f32

  k_convw<<<128, 192, 0, stream>>>(W1, W2, Wt1r, Wt2);
  k_fusew<<<128, 128, 0, stream>>>(Wq, Wk, W1, Wqc, Wkc);
  k_prep<<<E_N/256, 256, 0, stream>>>(nc, eidx, cen4);
  k_topk<<<E_N/8, 256, 0, stream>>>(cen4, idx);
  k_qkv<<<E_N/8, 128, 0, stream>>>(ef, Wq, Wk, Wv, Wqc, Wkc, b1, Wg1, bg1, Wg2, bg2,
                                   qf, kf, vf, qW1, kW1, gates);
  k_mlp<<<E_N*KNB/64, 256, 0, stream>>>(idx, qf, kf, cen4, qW1, kW1, Wt1r, Wt2,
                                        W1, b2, W3, b3, centers, widths, scores);
  k_combine<<<E_N, 128, 0, stream>>>(scores, idx, vf, gates, cen4, ef, ec, upd, outc);
  k_out<<<E_N/8, 256, 0, stream>>>(upd, ef, Wo, bo, gamma, beta, outf);
}

// Round 10
// 223.200 us; speedup vs baseline: 1.3082x; 1.0447x over previous
//
#include <hip/hip_runtime.h>
#include <math.h>

#define E_N   8192
#define HID   128
#define NRAD  64
#define KNB   32
#define CUTF  10.0f
#define LNEPS 1e-5f

typedef unsigned short u16;
typedef unsigned int   u32;
typedef unsigned long long u64;
typedef __bf16 bf16x8 __attribute__((ext_vector_type(8)));
typedef u16    u16x8  __attribute__((ext_vector_type(8)));
typedef float  f32x4  __attribute__((ext_vector_type(4)));

__device__ __forceinline__ u16 f2bf(float f) {          // native HW cvt (RNE)
  __bf16 h = (__bf16)f;
  return __builtin_bit_cast(u16, h);
}
__device__ __forceinline__ float bf2f(u16 v) {
  return __uint_as_float(((u32)v) << 16);
}

__device__ __forceinline__ u64 shflx64(u64 v, int m) {
  int lo = __shfl_xor((int)(v & 0xffffffffull), m, 64);
  int hi = __shfl_xor((int)(v >> 32), m, 64);
  return ((u64)(unsigned)hi << 32) | (unsigned)lo;
}

// monotone-u32 key of squared distance; fmaf-pinned so pass1/pass2 agree bitwise
__device__ __forceinline__ u32 d2key(const float4 me, const float4 c) {
  float dot = fmaf(me.x, c.x, fmaf(me.y, c.y, me.z * c.z));
  float d2  = fmaf(-2.0f, dot, me.w + c.w);     // gram trick, as in reference
  u32 u = __float_as_uint(d2);
  return u ^ (((u32)((int)u >> 31)) | 0x80000000u);
}

// ---------------- kernel 0a: bf16 weight prep (rbf block of W1, W2), transposed ----------------
__global__ void k_convw(const float* __restrict__ W1, const float* __restrict__ W2,
                        u16* __restrict__ Wt1r, u16* __restrict__ Wt2) {
  int b = blockIdx.x;            // output col 0..127
  int t = threadIdx.x;           // 0..191
  if (t < 64)       Wt1r[b*64 + t]        = f2bf(W1[(256+t)*HID + b]);   // rbf rows 256..319
  else if (t < 192) Wt2[b*HID + (t-64)]   = f2bf(W2[(t-64)*HID + b]);
}

// ---------------- kernel 0b: fused weight products Wqc = Wq@W1[0:128], Wkc = Wk@W1[128:256] ----------------
__global__ void k_fusew(const float* __restrict__ Wq, const float* __restrict__ Wk,
                        const float* __restrict__ W1,
                        float* __restrict__ Wqc, float* __restrict__ Wkc) {
  int r = blockIdx.x, o = threadIdx.x;   // 128 x 128
  float a = 0.f, b = 0.f;
  #pragma unroll 8
  for (int m = 0; m < 128; ++m) {
    a = fmaf(Wq[r*128+m], W1[m*128+o], a);
    b = fmaf(Wk[r*128+m], W1[(128+m)*128+o], b);
  }
  Wqc[r*128+o] = a; Wkc[r*128+o] = b;
}

// ---------------- kernel 1: edge centers + squared norms (packed float4) ----------------
__global__ void k_prep(const float* __restrict__ nc, const int* __restrict__ ei,
                       float4* __restrict__ cen4) {
  int e = blockIdx.x * 256 + threadIdx.x;
  if (e >= E_N) return;
  int a = ei[e], b = ei[E_N + e];
  float x = (nc[a*3+0] + nc[b*3+0]) * 0.5f;
  float y = (nc[a*3+1] + nc[b*3+1]) * 0.5f;
  float z = (nc[a*3+2] + nc[b*3+2]) * 0.5f;
  cen4[e] = make_float4(x, y, z, x*x + y*y + z*z);
}

// ---------------- kernel 2: top-K, 8 rows/block, two-pass prune + exact lex rank ----------------
__global__ __launch_bounds__(256) void k_topk(const float4* __restrict__ cen4,
                                              int* __restrict__ idxo) {
  const int row0 = blockIdx.x * 8;
  const int t = threadIdx.x;
  const int lane = t & 63, w = t >> 6;
  __shared__ __align__(16) u32 smin[8][256];   // 8 KiB
  __shared__ __align__(16) u64 comp[2048];     // 16 KiB survivor buffer
  __shared__ u32 sU[8];
  __shared__ u32 scnt, scnt_r[8];
  __shared__ u64 wred[4];
  __shared__ u64 winner;

  if (t == 0) scnt = 0;
  if (t < 8) scnt_r[t] = 0;

  float4 me[8];
  #pragma unroll
  for (int r = 0; r < 8; ++r) me[r] = cen4[row0 + r];

  // ---- pass 1: running mins for 8 rows ----
  u32 mn[8];
  #pragma unroll
  for (int r = 0; r < 8; ++r) mn[r] = 0xFFFFFFFFu;
  for (int s = 0; s < 32; ++s) {
    float4 c = cen4[t + (s << 8)];
    #pragma unroll
    for (int r = 0; r < 8; ++r) {
      u32 k = d2key(me[r], c);
      mn[r] = k < mn[r] ? k : mn[r];
    }
  }
  #pragma unroll
  for (int r = 0; r < 8; ++r) smin[r][t] = mn[r];
  __syncthreads();

  // ---- per-row bound: wave w handles rows 2w, 2w+1; in-wave radix bisect ----
  #pragma unroll
  for (int rr = 0; rr < 2; ++rr) {
    const int r = w*2 + rr;
    uint4 vv = *(const uint4*)&smin[r][lane*4];
    u32 P = 0;
    u32 rem = 31;
    #pragma unroll 1
    for (int b = 31; b >= 12; --b) {
      u32 bit = 1u << b;
      bool pm0 = ((u64)(vv.x ^ P) >> (b+1)) == 0ull;
      bool pm1 = ((u64)(vv.y ^ P) >> (b+1)) == 0ull;
      bool pm2 = ((u64)(vv.z ^ P) >> (b+1)) == 0ull;
      bool pm3 = ((u64)(vv.w ^ P) >> (b+1)) == 0ull;
      u32 c0 = (u32)__popcll(__ballot(pm0 && !(vv.x & bit)))
             + (u32)__popcll(__ballot(pm1 && !(vv.y & bit)))
             + (u32)__popcll(__ballot(pm2 && !(vv.z & bit)))
             + (u32)__popcll(__ballot(pm3 && !(vv.w & bit)));
      if (rem >= c0) { P |= bit; rem -= c0; }
    }
    if (lane == 0) sU[r] = P | 0xFFFu;
  }
  __syncthreads();

  // ---- pass 2: recompute keys, compact survivors ----
  u32 Ur[8];
  #pragma unroll
  for (int r = 0; r < 8; ++r) Ur[r] = sU[r];
  for (int s = 0; s < 32; ++s) {
    float4 c = cen4[t + (s << 8)];
    #pragma unroll
    for (int r = 0; r < 8; ++r) {
      u32 k = d2key(me[r], c);
      if (k <= Ur[r]) {
        u32 pos = atomicAdd(&scnt, 1u);
        atomicAdd(&scnt_r[r], 1u);
        if (pos < 2048u)
          comp[pos] = ((u64)r << 45) | (((u64)k) << 13) | (u32)(t + (s << 8));
      }
    }
  }
  __syncthreads();
  const int cnt = (int)scnt;

  if (cnt <= 2048) {
    u32 off[8];
    off[0] = 0;
    #pragma unroll
    for (int r = 1; r < 8; ++r) off[r] = off[r-1] + scnt_r[r-1];
    for (int i = t; i < cnt; i += 256) {
      u64 mev = comp[i];
      int rk = 0;
      int j2 = 0;
      for (; j2 + 2 <= cnt; j2 += 2) {
        ulonglong2 pr = *(const ulonglong2*)&comp[j2];
        rk += (pr.x < mev) ? 1 : 0;
        rk += (pr.y < mev) ? 1 : 0;
      }
      if (j2 < cnt) rk += (comp[j2] < mev) ? 1 : 0;
      int r = (int)(mev >> 45);
      int rank = rk - (int)off[r];
      if (rank < KNB) idxo[(row0 + r)*KNB + rank] = (int)(mev & 0x1FFFull);
    }
  } else {
    // overflow fallback (never taken statistically): exact per-row extract-min
    for (int r = 0; r < 8; ++r) {
      float4 mer = cen4[row0 + r];
      u32 taken = 0;
      for (int kk2 = 0; kk2 < KNB; ++kk2) {
        u64 lk = 0xFFFFFFFFFFFFFFFFull;
        for (int s = 0; s < 32; ++s) {
          if (taken & (1u << s)) continue;
          float4 c = cen4[t + (s << 8)];
          u64 kx = (((u64)d2key(mer, c)) << 13) | (u32)(t + (s << 8));
          lk = kx < lk ? kx : lk;
        }
        #pragma unroll
        for (int m = 1; m < 64; m <<= 1) {
          u64 o = shflx64(lk, m);
          lk = o < lk ? o : lk;
        }
        if (lane == 0) wred[w] = lk;
        __syncthreads();
        if (t == 0) {
          u64 w0 = wred[0] < wred[1] ? wred[0] : wred[1];
          u64 w1 = wred[2] < wred[3] ? wred[2] : wred[3];
          winner = w0 < w1 ? w0 : w1;
          idxo[(row0 + r)*KNB + kk2] = (int)(winner & 0x1FFFull);
        }
        __syncthreads();
        u64 jw = winner & 0x1FFFull;
        if (((u32)jw & 255u) == (u32)t) taken |= 1u << ((u32)jw >> 8);
        __syncthreads();
      }
    }
  }
}

// ---------------- kernel 3: q + fused-projection rows + packed bf16 j-side + gates ----------------
// outputs: qf (f32), qW1 (f32, +b1), kjp (bf16: [kW1 row | k row], 256 u16/edge),
// vfb (bf16 v row), gates.
__global__ __launch_bounds__(128) void k_qkv(const float* __restrict__ ef,
    const float* __restrict__ Wq, const float* __restrict__ Wk, const float* __restrict__ Wv,
    const float* __restrict__ Wqc, const float* __restrict__ Wkc, const float* __restrict__ b1,
    const float* __restrict__ Wg1, const float* __restrict__ bg1,
    const float* __restrict__ Wg2, const float* __restrict__ bg2,
    float* __restrict__ qf, float* __restrict__ qW1,
    u16* __restrict__ kjp, u16* __restrict__ vfb, float* __restrict__ gates) {
  const int o = threadIdx.x;
  const int e0 = blockIdx.x * 8;
  __shared__ float efs[8][128];
  __shared__ float vs[8][128];
  __shared__ float gred[8][2];

  #pragma unroll
  for (int e = 0; e < 8; ++e) efs[e][o] = ef[(e0+e)*HID + o];
  __syncthreads();

  float aq[8] = {0}, ak[8] = {0}, av[8] = {0}, aqc[8] = {0}, akc[8] = {0};
  #pragma unroll 4
  for (int d = 0; d < 128; ++d) {
    float wq = Wq[d*128+o], wk = Wk[d*128+o], wv = Wv[d*128+o];
    float wc1 = Wqc[d*128+o], wc2 = Wkc[d*128+o];
    #pragma unroll
    for (int e = 0; e < 8; ++e) {
      float a = efs[e][d];
      aq[e]  = fmaf(a, wq,  aq[e]);
      ak[e]  = fmaf(a, wk,  ak[e]);
      av[e]  = fmaf(a, wv,  av[e]);
      aqc[e] = fmaf(a, wc1, aqc[e]);
      akc[e] = fmaf(a, wc2, akc[e]);
    }
  }
  float bb1 = b1[o];
  #pragma unroll
  for (int e = 0; e < 8; ++e) {
    qf[(e0+e)*HID+o]  = aq[e];
    qW1[(e0+e)*HID+o] = aqc[e] + bb1;
    kjp[(size_t)(e0+e)*256 + o]       = f2bf(akc[e]);   // kW1 part
    kjp[(size_t)(e0+e)*256 + 128 + o] = f2bf(ak[e]);    // k part (for q.k dot)
    vfb[(size_t)(e0+e)*128 + o]       = f2bf(av[e]);
    vs[e][o] = av[e];
  }
  __syncthreads();

  float ag[8] = {0};
  #pragma unroll 4
  for (int d = 0; d < 128; ++d) {
    float wg = Wg1[d*128+o];
    #pragma unroll
    for (int e = 0; e < 8; ++e) ag[e] = fmaf(vs[e][d], wg, ag[e]);
  }
  float bgo = bg1[o], w2 = Wg2[o];
  const int lane = o & 63, w = o >> 6;
  #pragma unroll
  for (int e = 0; e < 8; ++e) {
    float g = ag[e] + bgo;
    g = g / (1.0f + __expf(-g));
    float part = g * w2;
    #pragma unroll
    for (int m = 1; m < 64; m <<= 1) part += __shfl_xor(part, m, 64);
    if (lane == 0) gred[e][w] = part;
  }
  __syncthreads();
  if (o < 8) gates[e0+o] = 1.0f / (1.0f + __expf(-(gred[o][0] + gred[o][1] + bg2[0])));
}

// ---------------- kernel 5: fused attention MLP -> scores (bf16 MFMA, bf16 packed gathers) ----------------
__global__ __launch_bounds__(256) void k_mlp(
    const int* __restrict__ idx,
    const float* __restrict__ qf,
    const float4* __restrict__ cen4,
    const float* __restrict__ qW1, const u16* __restrict__ kjp,
    const u16* __restrict__ Wt1r, const u16* __restrict__ Wt2,
    const float* __restrict__ W1,           // for w320 row
    const float* __restrict__ b2, const float* __restrict__ W3,
    const float* __restrict__ b3,
    const float* __restrict__ centers, const float* __restrict__ widths,
    float* __restrict__ scores) {
  __shared__ u16 sA[64*64];       // rbf tile, swizzled (8 KiB)
  __shared__ u16 sH[64*128];      // h tile, swizzled (16 KiB)
  __shared__ float spart[4][64];
  __shared__ float sQW[2][128];
  __shared__ float sDot[64];
  __shared__ float sDist[64];

  const int t  = threadIdx.x;
  const int w  = t >> 6, l = t & 63;
  const int l15 = l & 15, l4 = l >> 4;
  const int rowbase = blockIdx.x * 64;
  const int eBase = rowbase >> 5;           // two edges per block

  // ---- EARLY: issue bf16 kW1-part gathers for this thread's 16 epilogue rows ----
  // (latency hides under rbf staging + GEMM1)
  u16 kv[16][2];
  #pragma unroll
  for (int rt = 0; rt < 4; ++rt) {
    #pragma unroll
    for (int r = 0; r < 4; ++r) {
      int row = rt*16 + l4*4 + r;
      int jrow = idx[rowbase + row];
      #pragma unroll
      for (int ct = 0; ct < 2; ++ct)
        kv[rt*4+r][ct] = kjp[(size_t)jrow*256 + w*32 + ct*16 + l15];
    }
  }

  // ---- stage: dot + dist + rbf tile + per-edge qW1 rows ----
  const int srow = t >> 2, sb = t & 3;
  const int sp = rowbase + srow;
  const int se = sp >> 5;
  const int sj = idx[sp];
  // q.k dot: q f32 (contiguous, L2-hot) x k bf16 (from packed row), 4 lanes/row
  const u16x8* kb = (const u16x8*)(kjp + (size_t)sj*256 + 128 + sb*32);
  const float4* q4 = (const float4*)(qf + (size_t)se*HID) + sb*8;
  float dt = 0.f;
  #pragma unroll
  for (int i = 0; i < 4; ++i) {
    u16x8 kv8 = kb[i];
    float4 qa = q4[i*2], qb = q4[i*2+1];
    dt += bf2f(kv8[0])*qa.x + bf2f(kv8[1])*qa.y + bf2f(kv8[2])*qa.z + bf2f(kv8[3])*qa.w
        + bf2f(kv8[4])*qb.x + bf2f(kv8[5])*qb.y + bf2f(kv8[6])*qb.z + bf2f(kv8[7])*qb.w;
  }
  dt += __shfl_xor(dt, 1, 64);
  dt += __shfl_xor(dt, 2, 64);
  // geometry
  float4 ce = cen4[se], cj = cen4[sj];
  float ddx = ce.x - cj.x, ddy = ce.y - cj.y, ddz = ce.z - cj.z;
  const float sdist = sqrtf(ddx*ddx + ddy*ddy + ddz*ddz);
  const float sincut = (sdist <= CUTF) ? 1.0f : 0.0f;
  if (sb == 0) { sDot[srow] = dt; sDist[srow] = sdist; }
  {
    u16 tmp[16];
    #pragma unroll
    for (int i4 = 0; i4 < 4; ++i4) {
      float4 cc = *(const float4*)(centers + sb*16 + i4*4);
      float4 ww = *(const float4*)(widths  + sb*16 + i4*4);
      float c4[4] = {cc.x,cc.y,cc.z,cc.w}, w4[4] = {ww.x,ww.y,ww.z,ww.w};
      #pragma unroll
      for (int jj = 0; jj < 4; ++jj) {
        float df = sdist - c4[jj];
        tmp[i4*4+jj] = f2bf(__expf(-w4[jj]*df*df) * sincut);
      }
    }
    #pragma unroll
    for (int g = 0; g < 2; ++g) {
      u16x8 vv;
      #pragma unroll
      for (int jj = 0; jj < 8; ++jj) vv[jj] = tmp[g*8+jj];
      int widx = (srow*64 + sb*16 + g*8) ^ ((srow & 7) << 3);
      *(u16x8*)(&sA[widx]) = vv;
    }
  }
  sQW[t >> 7][t & 127] = qW1[(size_t)(eBase + (t >> 7))*HID + (t & 127)];
  __syncthreads();

  f32x4 acc[4][2];
  #pragma unroll
  for (int rt = 0; rt < 4; ++rt)
    #pragma unroll
    for (int ct = 0; ct < 2; ++ct) acc[rt][ct] = (f32x4){0.f,0.f,0.f,0.f};

  // ---- GEMM1: rbf (K=64) ----
  #pragma unroll
  for (int ks = 0; ks < 2; ++ks) {
    bf16x8 af[4], bfr[2];
    #pragma unroll
    for (int rt = 0; rt < 4; ++rt) {
      int row = rt*16 + l15;
      int aidx = (row*64 + ks*32 + l4*8) ^ ((row & 7) << 3);
      af[rt] = *(const bf16x8*)(&sA[aidx]);
    }
    #pragma unroll
    for (int ct = 0; ct < 2; ++ct) {
      int col = w*32 + ct*16 + l15;
      bfr[ct] = *(const bf16x8*)(&Wt1r[col*64 + ks*32 + l4*8]);
    }
    #pragma unroll
    for (int rt = 0; rt < 4; ++rt)
      #pragma unroll
      for (int ct = 0; ct < 2; ++ct)
        acc[rt][ct] = __builtin_amdgcn_mfma_f32_16x16x32_bf16(af[rt], bfr[ct], acc[rt][ct], 0, 0, 0);
  }

  // ---- epilogue 1: + qW1[e] + kW1[j](bf16 reg) + dot*w320, silu -> sH bf16 ----
  {
    float w320[2];
    #pragma unroll
    for (int ct = 0; ct < 2; ++ct) {
      int col = w*32 + ct*16 + l15;
      w320[ct] = W1[320*HID + col];
    }
    #pragma unroll
    for (int rt = 0; rt < 4; ++rt) {
      #pragma unroll
      for (int r = 0; r < 4; ++r) {
        int row = rt*16 + l4*4 + r;
        float dv = sDot[row];
        int eh = row >> 5;
        #pragma unroll
        for (int ct = 0; ct < 2; ++ct) {
          int col = w*32 + ct*16 + l15;
          float x = acc[rt][ct][r] + sQW[eh][col] + bf2f(kv[rt*4+r][ct]) + dv*w320[ct];
          float h = x / (1.0f + __expf(-x));
          sH[(row*128 + col) ^ ((row & 7) << 3)] = f2bf(h);
        }
      }
    }
  }
  __syncthreads();

  #pragma unroll
  for (int rt = 0; rt < 4; ++rt)
    #pragma unroll
    for (int ct = 0; ct < 2; ++ct) acc[rt][ct] = (f32x4){0.f,0.f,0.f,0.f};

  // ---- GEMM2: h @ W2 ----
  #pragma unroll
  for (int ks = 0; ks < 4; ++ks) {
    bf16x8 af[4], bfr[2];
    #pragma unroll
    for (int rt = 0; rt < 4; ++rt) {
      int row = rt*16 + l15;
      int aidx = (row*128 + ks*32 + l4*8) ^ ((row & 7) << 3);
      af[rt] = *(const bf16x8*)(&sH[aidx]);
    }
    #pragma unroll
    for (int ct = 0; ct < 2; ++ct) {
      int col = w*32 + ct*16 + l15;
      bfr[ct] = *(const bf16x8*)(&Wt2[col*128 + ks*32 + l4*8]);
    }
    #pragma unroll
    for (int rt = 0; rt < 4; ++rt)
      #pragma unroll
      for (int ct = 0; ct < 2; ++ct)
        acc[rt][ct] = __builtin_amdgcn_mfma_f32_16x16x32_bf16(af[rt], bfr[ct], acc[rt][ct], 0, 0, 0);
  }

  // ---- epilogue 2: silu, dot W3, reduce ----
  {
    float b2r[2], w3r[2];
    #pragma unroll
    for (int ct = 0; ct < 2; ++ct) {
      int col = w*32 + ct*16 + l15;
      b2r[ct] = b2[col]; w3r[ct] = W3[col];
    }
    #pragma unroll
    for (int rt = 0; rt < 4; ++rt) {
      #pragma unroll
      for (int r = 0; r < 4; ++r) {
        float part = 0.f;
        #pragma unroll
        for (int ct = 0; ct < 2; ++ct) {
          float x = acc[rt][ct][r] + b2r[ct];
          float h = x / (1.0f + __expf(-x));
          part = fmaf(h, w3r[ct], part);
        }
        part += __shfl_xor(part, 1, 64);
        part += __shfl_xor(part, 2, 64);
        part += __shfl_xor(part, 4, 64);
        part += __shfl_xor(part, 8, 64);
        if (l15 == 0) spart[w][rt*16 + l4*4 + r] = part;
      }
    }
  }
  __syncthreads();
  if (t < 64) {
    int p = rowbase + t;
    float raw = spart[0][t] + spart[1][t] + spart[2][t] + spart[3][t] + b3[0];
    scores[p] = (sDist[t] <= CUTF) ? raw : 0.0f;
  }
}

// ---------------- kernel 6: softmax + weighted V (bf16 gather) + coord update ----------------
__global__ void k_combine(const float* __restrict__ scores, const int* __restrict__ idx,
    const u16* __restrict__ vfb, const float* __restrict__ gates,
    const float4* __restrict__ cen4, const float* __restrict__ ef,
    const float* __restrict__ ec, float* __restrict__ upd, float* __restrict__ outc) {
  int e = blockIdx.x, t = threadIdx.x;   // 128 threads
  __shared__ float wk[KNB];
  __shared__ float sd[3][KNB];
  __shared__ int jj[KNB];
  if (t < 64) {
    float sc = (t < KNB) ? scores[e*KNB + t] : -1e30f;
    float m = sc;
    #pragma unroll
    for (int mm = 1; mm < 32; mm <<= 1) m = fmaxf(m, __shfl_xor(m, mm, 64));
    m = fmaxf(m, 0.0f);
    float ex = (t < KNB) ? __expf(sc - m) : 0.0f;
    float Z = ex;
    #pragma unroll
    for (int mm = 1; mm < 32; mm <<= 1) Z += __shfl_xor(Z, mm, 64);
    Z += 8160.0f * __expf(-m);             // (E-K) zero-score tail
    if (t < KNB) {
      float wv = ex / Z;
      int j = idx[e*KNB + t];
      jj[t] = j; wk[t] = wv;
      float g = wv * gates[j];
      float4 ce = cen4[e], cj = cen4[j];
      sd[0][t] = g*(ce.x - cj.x);
      sd[1][t] = g*(ce.y - cj.y);
      sd[2][t] = g*(ce.z - cj.z);
    }
  }
  __syncthreads();
  float acc = 0.0f;
  #pragma unroll 4
  for (int kk = 0; kk < KNB; ++kk)
    acc = fmaf(wk[kk], bf2f(vfb[(size_t)jj[kk]*HID + t]), acc);
  upd[e*HID + t] = ef[e*HID + t] + acc;
  if (t < 3) {
    float csum = 0.0f;
    #pragma unroll 4
    for (int kk = 0; kk < KNB; ++kk) csum += sd[t][kk];
    outc[e*3 + t] = ec[e*3 + t] + csum;
  }
}

// ---------------- kernel 7: output projection + residual + LayerNorm, 8 edges/block ----------------
__global__ __launch_bounds__(256) void k_out(const float* __restrict__ upd,
    const float* __restrict__ ef,
    const float* __restrict__ Wo, const float* __restrict__ bo,
    const float* __restrict__ gamma, const float* __restrict__ beta,
    float* __restrict__ outf) {
  const int t = threadIdx.x;
  const int e0 = blockIdx.x * 8;
  const int o = t & 127, h = t >> 7;
  __shared__ float us[8][128];
  __shared__ float xs[8][128];
  #pragma unroll
  for (int i = 0; i < 4; ++i) {
    int ii = t + i*256;
    us[ii >> 7][ii & 127] = upd[e0*HID + ii];
  }
  __syncthreads();
  float acc[4] = {0,0,0,0};
  #pragma unroll 4
  for (int d = 0; d < 128; ++d) {
    float wo = Wo[d*128+o];
    #pragma unroll
    for (int i = 0; i < 4; ++i) acc[i] = fmaf(us[h*4+i][d], wo, acc[i]);
  }
  float bb = bo[o];
  #pragma unroll
  for (int i = 0; i < 4; ++i) {
    int e = h*4+i;
    xs[e][o] = ef[(e0+e)*HID + o] + acc[i] + bb;
  }
  __syncthreads();
  const int w = t >> 6, lane = t & 63;
  #pragma unroll
  for (int ii = 0; ii < 2; ++ii) {
    int e = w*2 + ii;
    float a = xs[e][lane], b = xs[e][64+lane];
    float s1 = a + b, s2 = a*a + b*b;
    #pragma unroll
    for (int m = 1; m < 64; m <<= 1) {
      s1 += __shfl_xor(s1, m, 64);
      s2 += __shfl_xor(s2, m, 64);
    }
    float mu = s1 * (1.0f/128.0f);
    float var = s2 * (1.0f/128.0f) - mu*mu;
    float rs = rsqrtf(var + LNEPS);
    outf[(e0+e)*HID + lane]      = (a - mu)*rs*gamma[lane]      + beta[lane];
    outf[(e0+e)*HID + 64 + lane] = (b - mu)*rs*gamma[64+lane]   + beta[64+lane];
  }
}

extern "C" void kernel_launch(void* const* d_in, const int* in_sizes, int n_in,
                              void* d_out, int out_size, void* d_ws, size_t ws_size,
                              hipStream_t stream) {
  const float* ef   = (const float*)d_in[0];
  const float* ec   = (const float*)d_in[1];
  const float* nc   = (const float*)d_in[2];
  const float* Wq   = (const float*)d_in[3];
  const float* Wk   = (const float*)d_in[4];
  const float* Wv   = (const float*)d_in[5];
  const float* W1   = (const float*)d_in[6];
  const float* b1   = (const float*)d_in[7];
  const float* W2   = (const float*)d_in[8];
  const float* b2   = (const float*)d_in[9];
  const float* W3   = (const float*)d_in[10];
  const float* b3   = (const float*)d_in[11];
  const float* Wg1  = (const float*)d_in[12];
  const float* bg1  = (const float*)d_in[13];
  const float* Wg2  = (const float*)d_in[14];
  const float* bg2  = (const float*)d_in[15];
  const float* Wo   = (const float*)d_in[16];
  const float* bo   = (const float*)d_in[17];
  const float* gamma= (const float*)d_in[18];
  const float* beta = (const float*)d_in[19];
  const float* centers = (const float*)d_in[20];
  const float* widths  = (const float*)d_in[21];
  const int*   eidx    = (const int*)d_in[22];

  float* outf = (float*)d_out;
  float* outc = outf + (size_t)E_N * HID;

  // workspace layout (16B-aligned chunks first)
  float4* cen4 = (float4*)d_ws;                        // 8192 * 16B
  u16*   kjp   = (u16*)(cen4 + E_N);                   // E * 256 bf16 (4 MB)
  u16*   vfb   = kjp + (size_t)E_N*256;                // E * 128 bf16 (2 MB)
  u16*   Wt1r  = vfb + (size_t)E_N*128;                // 128*64 bf16
  u16*   Wt2   = Wt1r + 128*64;                        // 128*128 bf16
  int*   idx   = (int*)(Wt2 + 128*128);
  float* qf    = (float*)(idx + E_N*KNB);
  float* qW1   = qf + (size_t)E_N*HID;
  float* scores= qW1 + (size_t)E_N*HID;
  float* gates = scores + E_N*KNB;
  float* upd   = gates + E_N;
  float* Wqc   = upd + (size_t)E_N*HID;                // 128*128 f32
  float* Wkc   = Wqc + 128*128;                        // 128*128 f32

  k_convw<<<128, 192, 0, stream>>>(W1, W2, Wt1r, Wt2);
  k_fusew<<<128, 128, 0, stream>>>(Wq, Wk, W1, Wqc, Wkc);
  k_prep<<<E_N/256, 256, 0, stream>>>(nc, eidx, cen4);
  k_topk<<<E_N/8, 256, 0, stream>>>(cen4, idx);
  k_qkv<<<E_N/8, 128, 0, stream>>>(ef, Wq, Wk, Wv, Wqc, Wkc, b1, Wg1, bg1, Wg2, bg2,
                                   qf, qW1, kjp, vfb, gates);
  k_mlp<<<E_N*KNB/64, 256, 0, stream>>>(idx, qf, cen4, qW1, kjp, Wt1r, Wt2,
                                        W1, b2, W3, b3, centers, widths, scores);
  k_combine<<<E_N, 128, 0, stream>>>(scores, idx, vfb, gates, cen4, ef, ec, upd, outc);
  k_out<<<E_N/8, 256, 0, stream>>>(upd, ef, Wo, bo, gamma, beta, outf);
}

// Round 11
// 222.737 us; speedup vs baseline: 1.3110x; 1.0021x over previous
//
#include <hip/hip_runtime.h>
#include <math.h>

#define E_N   8192
#define HID   128
#define NRAD  64
#define KNB   32
#define CUTF  10.0f
#define LNEPS 1e-5f

typedef unsigned short u16;
typedef unsigned int   u32;
typedef unsigned long long u64;
typedef __bf16 bf16x8 __attribute__((ext_vector_type(8)));
typedef u16    u16x8  __attribute__((ext_vector_type(8)));
typedef float  f32x4  __attribute__((ext_vector_type(4)));

__device__ __forceinline__ u16 f2bf(float f) {          // native HW cvt (RNE)
  __bf16 h = (__bf16)f;
  return __builtin_bit_cast(u16, h);
}
__device__ __forceinline__ float bf2f(u16 v) {
  return __uint_as_float(((u32)v) << 16);
}

__device__ __forceinline__ u64 shflx64(u64 v, int m) {
  int lo = __shfl_xor((int)(v & 0xffffffffull), m, 64);
  int hi = __shfl_xor((int)(v >> 32), m, 64);
  return ((u64)(unsigned)hi << 32) | (unsigned)lo;
}

// monotone-u32 key of squared distance; fmaf-pinned so pass1/pass2 agree bitwise
__device__ __forceinline__ u32 d2key(const float4 me, const float4 c) {
  float dot = fmaf(me.x, c.x, fmaf(me.y, c.y, me.z * c.z));
  float d2  = fmaf(-2.0f, dot, me.w + c.w);     // gram trick, as in reference
  u32 u = __float_as_uint(d2);
  return u ^ (((u32)((int)u >> 31)) | 0x80000000u);
}

// ---------------- kernel 0: merged prep (weights bf16 / fused products / centers) ----------------
__global__ __launch_bounds__(256) void k_pre(
    const float* __restrict__ W1, const float* __restrict__ W2,
    const float* __restrict__ Wq, const float* __restrict__ Wk,
    const float* __restrict__ nc, const int* __restrict__ ei,
    u16* __restrict__ Wt1r, u16* __restrict__ Wt2,
    float* __restrict__ Wqc, float* __restrict__ Wkc,
    float4* __restrict__ cen4) {
  const int b = blockIdx.x, t = threadIdx.x;
  if (b < 128) {
    if (t < 64)       Wt1r[b*64 + t]      = f2bf(W1[(256+t)*HID + b]);   // rbf rows 256..319
    else if (t < 192) Wt2[b*HID + (t-64)] = f2bf(W2[(t-64)*HID + b]);
  } else if (b < 256) {
    const int r = b - 128, o = t & 127;
    float a = 0.f;
    if (t < 128) {
      #pragma unroll 8
      for (int m = 0; m < 128; ++m) a = fmaf(Wq[r*128+m], W1[m*128+o], a);
      Wqc[r*128+o] = a;
    } else {
      #pragma unroll 8
      for (int m = 0; m < 128; ++m) a = fmaf(Wk[r*128+m], W1[(128+m)*128+o], a);
      Wkc[r*128+o] = a;
    }
  } else {
    const int e = (b - 256)*256 + t;
    if (e < E_N) {
      int a = ei[e], bb = ei[E_N + e];
      float x = (nc[a*3+0] + nc[bb*3+0]) * 0.5f;
      float y = (nc[a*3+1] + nc[bb*3+1]) * 0.5f;
      float z = (nc[a*3+2] + nc[bb*3+2]) * 0.5f;
      cen4[e] = make_float4(x, y, z, x*x + y*y + z*z);
    }
  }
}

// ---------------- kernel 2: top-K, 8 rows/block, two-pass prune + exact lex rank ----------------
__global__ __launch_bounds__(256) void k_topk(const float4* __restrict__ cen4,
                                              int* __restrict__ idxo) {
  const int row0 = blockIdx.x * 8;
  const int t = threadIdx.x;
  const int lane = t & 63, w = t >> 6;
  __shared__ __align__(16) u32 smin[8][256];   // 8 KiB
  __shared__ __align__(16) u64 comp[2048];     // 16 KiB survivor buffer
  __shared__ u32 sU[8];
  __shared__ u32 scnt, scnt_r[8];
  __shared__ u64 wred[4];
  __shared__ u64 winner;

  if (t == 0) scnt = 0;
  if (t < 8) scnt_r[t] = 0;

  float4 me[8];
  #pragma unroll
  for (int r = 0; r < 8; ++r) me[r] = cen4[row0 + r];

  // ---- pass 1: running mins for 8 rows ----
  u32 mn[8];
  #pragma unroll
  for (int r = 0; r < 8; ++r) mn[r] = 0xFFFFFFFFu;
  for (int s = 0; s < 32; ++s) {
    float4 c = cen4[t + (s << 8)];
    #pragma unroll
    for (int r = 0; r < 8; ++r) {
      u32 k = d2key(me[r], c);
      mn[r] = k < mn[r] ? k : mn[r];
    }
  }
  #pragma unroll
  for (int r = 0; r < 8; ++r) smin[r][t] = mn[r];
  __syncthreads();

  // ---- per-row bound: wave w handles rows 2w, 2w+1; in-wave radix bisect ----
  #pragma unroll
  for (int rr = 0; rr < 2; ++rr) {
    const int r = w*2 + rr;
    uint4 vv = *(const uint4*)&smin[r][lane*4];
    u32 P = 0;
    u32 rem = 31;
    #pragma unroll 1
    for (int b = 31; b >= 12; --b) {
      u32 bit = 1u << b;
      bool pm0 = ((u64)(vv.x ^ P) >> (b+1)) == 0ull;
      bool pm1 = ((u64)(vv.y ^ P) >> (b+1)) == 0ull;
      bool pm2 = ((u64)(vv.z ^ P) >> (b+1)) == 0ull;
      bool pm3 = ((u64)(vv.w ^ P) >> (b+1)) == 0ull;
      u32 c0 = (u32)__popcll(__ballot(pm0 && !(vv.x & bit)))
             + (u32)__popcll(__ballot(pm1 && !(vv.y & bit)))
             + (u32)__popcll(__ballot(pm2 && !(vv.z & bit)))
             + (u32)__popcll(__ballot(pm3 && !(vv.w & bit)));
      if (rem >= c0) { P |= bit; rem -= c0; }
    }
    if (lane == 0) sU[r] = P | 0xFFFu;
  }
  __syncthreads();

  // ---- pass 2: recompute keys, compact survivors ----
  u32 Ur[8];
  #pragma unroll
  for (int r = 0; r < 8; ++r) Ur[r] = sU[r];
  for (int s = 0; s < 32; ++s) {
    float4 c = cen4[t + (s << 8)];
    #pragma unroll
    for (int r = 0; r < 8; ++r) {
      u32 k = d2key(me[r], c);
      if (k <= Ur[r]) {
        u32 pos = atomicAdd(&scnt, 1u);
        atomicAdd(&scnt_r[r], 1u);
        if (pos < 2048u)
          comp[pos] = ((u64)r << 45) | (((u64)k) << 13) | (u32)(t + (s << 8));
      }
    }
  }
  __syncthreads();
  const int cnt = (int)scnt;

  if (cnt <= 2048) {
    u32 off[8];
    off[0] = 0;
    #pragma unroll
    for (int r = 1; r < 8; ++r) off[r] = off[r-1] + scnt_r[r-1];
    for (int i = t; i < cnt; i += 256) {
      u64 mev = comp[i];
      int rk = 0;
      int j2 = 0;
      for (; j2 + 2 <= cnt; j2 += 2) {
        ulonglong2 pr = *(const ulonglong2*)&comp[j2];
        rk += (pr.x < mev) ? 1 : 0;
        rk += (pr.y < mev) ? 1 : 0;
      }
      if (j2 < cnt) rk += (comp[j2] < mev) ? 1 : 0;
      int r = (int)(mev >> 45);
      int rank = rk - (int)off[r];
      if (rank < KNB) idxo[(row0 + r)*KNB + rank] = (int)(mev & 0x1FFFull);
    }
  } else {
    // overflow fallback (never taken statistically): exact per-row extract-min
    for (int r = 0; r < 8; ++r) {
      float4 mer = cen4[row0 + r];
      u32 taken = 0;
      for (int kk2 = 0; kk2 < KNB; ++kk2) {
        u64 lk = 0xFFFFFFFFFFFFFFFFull;
        for (int s = 0; s < 32; ++s) {
          if (taken & (1u << s)) continue;
          float4 c = cen4[t + (s << 8)];
          u64 kx = (((u64)d2key(mer, c)) << 13) | (u32)(t + (s << 8));
          lk = kx < lk ? kx : lk;
        }
        #pragma unroll
        for (int m = 1; m < 64; m <<= 1) {
          u64 o = shflx64(lk, m);
          lk = o < lk ? o : lk;
        }
        if (lane == 0) wred[w] = lk;
        __syncthreads();
        if (t == 0) {
          u64 w0 = wred[0] < wred[1] ? wred[0] : wred[1];
          u64 w1 = wred[2] < wred[3] ? wred[2] : wred[3];
          winner = w0 < w1 ? w0 : w1;
          idxo[(row0 + r)*KNB + kk2] = (int)(winner & 0x1FFFull);
        }
        __syncthreads();
        u64 jw = winner & 0x1FFFull;
        if (((u32)jw & 255u) == (u32)t) taken |= 1u << ((u32)jw >> 8);
        __syncthreads();
      }
    }
  }
}

// ---------------- kernel 3: q + fused-projection rows + packed bf16 j-side + gates ----------------
__global__ __launch_bounds__(128) void k_qkv(const float* __restrict__ ef,
    const float* __restrict__ Wq, const float* __restrict__ Wk, const float* __restrict__ Wv,
    const float* __restrict__ Wqc, const float* __restrict__ Wkc, const float* __restrict__ b1,
    const float* __restrict__ Wg1, const float* __restrict__ bg1,
    const float* __restrict__ Wg2, const float* __restrict__ bg2,
    float* __restrict__ qf, float* __restrict__ qW1,
    u16* __restrict__ kjp, u16* __restrict__ vfb, float* __restrict__ gates) {
  const int o = threadIdx.x;
  const int e0 = blockIdx.x * 8;
  __shared__ float efs[8][128];
  __shared__ float vs[8][128];
  __shared__ float gred[8][2];

  #pragma unroll
  for (int e = 0; e < 8; ++e) efs[e][o] = ef[(e0+e)*HID + o];
  __syncthreads();

  float aq[8] = {0}, ak[8] = {0}, av[8] = {0}, aqc[8] = {0}, akc[8] = {0};
  #pragma unroll 4
  for (int d = 0; d < 128; ++d) {
    float wq = Wq[d*128+o], wk = Wk[d*128+o], wv = Wv[d*128+o];
    float wc1 = Wqc[d*128+o], wc2 = Wkc[d*128+o];
    #pragma unroll
    for (int e = 0; e < 8; ++e) {
      float a = efs[e][d];
      aq[e]  = fmaf(a, wq,  aq[e]);
      ak[e]  = fmaf(a, wk,  ak[e]);
      av[e]  = fmaf(a, wv,  av[e]);
      aqc[e] = fmaf(a, wc1, aqc[e]);
      akc[e] = fmaf(a, wc2, akc[e]);
    }
  }
  float bb1 = b1[o];
  #pragma unroll
  for (int e = 0; e < 8; ++e) {
    qf[(e0+e)*HID+o]  = aq[e];
    qW1[(e0+e)*HID+o] = aqc[e] + bb1;
    kjp[(size_t)(e0+e)*256 + o]       = f2bf(akc[e]);   // kW1 part
    kjp[(size_t)(e0+e)*256 + 128 + o] = f2bf(ak[e]);    // k part (for q.k dot)
    vfb[(size_t)(e0+e)*128 + o]       = f2bf(av[e]);
    vs[e][o] = av[e];
  }
  __syncthreads();

  float ag[8] = {0};
  #pragma unroll 4
  for (int d = 0; d < 128; ++d) {
    float wg = Wg1[d*128+o];
    #pragma unroll
    for (int e = 0; e < 8; ++e) ag[e] = fmaf(vs[e][d], wg, ag[e]);
  }
  float bgo = bg1[o], w2 = Wg2[o];
  const int lane = o & 63, w = o >> 6;
  #pragma unroll
  for (int e = 0; e < 8; ++e) {
    float g = ag[e] + bgo;
    g = g / (1.0f + __expf(-g));
    float part = g * w2;
    #pragma unroll
    for (int m = 1; m < 64; m <<= 1) part += __shfl_xor(part, m, 64);
    if (lane == 0) gred[e][w] = part;
  }
  __syncthreads();
  if (o < 8) gates[e0+o] = 1.0f / (1.0f + __expf(-(gred[o][0] + gred[o][1] + bg2[0])));
}

// ---------------- kernel 5: fused MLP + softmax + combine (2 edges/block) ----------------
__global__ __launch_bounds__(256) void k_mlp(
    const int* __restrict__ idx,
    const float* __restrict__ qf,
    const float4* __restrict__ cen4,
    const float* __restrict__ qW1, const u16* __restrict__ kjp,
    const u16* __restrict__ vfb, const float* __restrict__ gates,
    const u16* __restrict__ Wt1r, const u16* __restrict__ Wt2,
    const float* __restrict__ W1,           // for w320 row
    const float* __restrict__ b2, const float* __restrict__ W3,
    const float* __restrict__ b3,
    const float* __restrict__ centers, const float* __restrict__ widths,
    const float* __restrict__ ef, const float* __restrict__ ec,
    float* __restrict__ upd, float* __restrict__ outc) {
  __shared__ u16 sA[64*64];       // rbf tile, swizzled (8 KiB)
  __shared__ u16 sH[64*128];      // kW1[j] tile -> in-place h tile (16 KiB)
  __shared__ float spart[4][64];
  __shared__ float sQW[2][128];
  __shared__ float sDot[64];
  __shared__ float sDist[64];
  __shared__ float sScore[64];
  __shared__ float swk[2][32];
  __shared__ int   sIdx[64];

  const int t  = threadIdx.x;
  const int w  = t >> 6, l = t & 63;
  const int l15 = l & 15, l4 = l >> 4;
  const int rowbase = blockIdx.x * 64;
  const int eBase = rowbase >> 5;           // two edges per block

  // ---- stage: kW1[j] tile (vectorized gather -> sH), dot, dist, rbf -> sA ----
  const int srow = t >> 2, sb = t & 3;
  const int sp = rowbase + srow;
  const int se = sp >> 5;
  const int sj = idx[sp];
  {
    const u16x8* kw = (const u16x8*)(kjp + (size_t)sj*256 + sb*32);
    #pragma unroll
    for (int g = 0; g < 4; ++g) {
      int widx = (srow*128 + sb*32 + g*8) ^ ((srow & 7) << 3);
      *(u16x8*)(&sH[widx]) = kw[g];
    }
  }
  // q.k dot: q f32 x k bf16 (packed row), 4 lanes/row
  const u16x8* kb = (const u16x8*)(kjp + (size_t)sj*256 + 128 + sb*32);
  const float4* q4 = (const float4*)(qf + (size_t)se*HID) + sb*8;
  float dt = 0.f;
  #pragma unroll
  for (int i = 0; i < 4; ++i) {
    u16x8 kv8 = kb[i];
    float4 qa = q4[i*2], qb = q4[i*2+1];
    dt += bf2f(kv8[0])*qa.x + bf2f(kv8[1])*qa.y + bf2f(kv8[2])*qa.z + bf2f(kv8[3])*qa.w
        + bf2f(kv8[4])*qb.x + bf2f(kv8[5])*qb.y + bf2f(kv8[6])*qb.z + bf2f(kv8[7])*qb.w;
  }
  dt += __shfl_xor(dt, 1, 64);
  dt += __shfl_xor(dt, 2, 64);
  // geometry
  float4 ce = cen4[se], cj = cen4[sj];
  float ddx = ce.x - cj.x, ddy = ce.y - cj.y, ddz = ce.z - cj.z;
  const float sdist = sqrtf(ddx*ddx + ddy*ddy + ddz*ddz);
  const float sincut = (sdist <= CUTF) ? 1.0f : 0.0f;
  if (sb == 0) { sDot[srow] = dt; sDist[srow] = sdist; }
  {
    u16 tmp[16];
    #pragma unroll
    for (int i4 = 0; i4 < 4; ++i4) {
      float4 cc = *(const float4*)(centers + sb*16 + i4*4);
      float4 ww = *(const float4*)(widths  + sb*16 + i4*4);
      float c4[4] = {cc.x,cc.y,cc.z,cc.w}, w4[4] = {ww.x,ww.y,ww.z,ww.w};
      #pragma unroll
      for (int jj = 0; jj < 4; ++jj) {
        float df = sdist - c4[jj];
        tmp[i4*4+jj] = f2bf(__expf(-w4[jj]*df*df) * sincut);
      }
    }
    #pragma unroll
    for (int g = 0; g < 2; ++g) {
      u16x8 vv;
      #pragma unroll
      for (int jj = 0; jj < 8; ++jj) vv[jj] = tmp[g*8+jj];
      int widx = (srow*64 + sb*16 + g*8) ^ ((srow & 7) << 3);
      *(u16x8*)(&sA[widx]) = vv;
    }
  }
  sQW[t >> 7][t & 127] = qW1[(size_t)(eBase + (t >> 7))*HID + (t & 127)];
  if (t < 64) sIdx[t] = idx[rowbase + t];
  __syncthreads();

  f32x4 acc[4][2];
  #pragma unroll
  for (int rt = 0; rt < 4; ++rt)
    #pragma unroll
    for (int ct = 0; ct < 2; ++ct) acc[rt][ct] = (f32x4){0.f,0.f,0.f,0.f};

  // ---- GEMM1: rbf (K=64) ----
  #pragma unroll
  for (int ks = 0; ks < 2; ++ks) {
    bf16x8 af[4], bfr[2];
    #pragma unroll
    for (int rt = 0; rt < 4; ++rt) {
      int row = rt*16 + l15;
      int aidx = (row*64 + ks*32 + l4*8) ^ ((row & 7) << 3);
      af[rt] = *(const bf16x8*)(&sA[aidx]);
    }
    #pragma unroll
    for (int ct = 0; ct < 2; ++ct) {
      int col = w*32 + ct*16 + l15;
      bfr[ct] = *(const bf16x8*)(&Wt1r[col*64 + ks*32 + l4*8]);
    }
    #pragma unroll
    for (int rt = 0; rt < 4; ++rt)
      #pragma unroll
      for (int ct = 0; ct < 2; ++ct)
        acc[rt][ct] = __builtin_amdgcn_mfma_f32_16x16x32_bf16(af[rt], bfr[ct], acc[rt][ct], 0, 0, 0);
  }

  // ---- epilogue 1: x = acc + qW1[e] + kW1[j](sH in-place) + dot*w320; silu -> sH ----
  {
    float w320[2];
    #pragma unroll
    for (int ct = 0; ct < 2; ++ct) {
      int col = w*32 + ct*16 + l15;
      w320[ct] = W1[320*HID + col];
    }
    #pragma unroll
    for (int rt = 0; rt < 4; ++rt) {
      #pragma unroll
      for (int r = 0; r < 4; ++r) {
        int row = rt*16 + l4*4 + r;
        float dv = sDot[row];
        int eh = row >> 5;
        #pragma unroll
        for (int ct = 0; ct < 2; ++ct) {
          int col = w*32 + ct*16 + l15;
          int hidx = (row*128 + col) ^ ((row & 7) << 3);
          float x = acc[rt][ct][r] + sQW[eh][col] + bf2f(sH[hidx]) + dv*w320[ct];
          float h = x / (1.0f + __expf(-x));
          sH[hidx] = f2bf(h);
        }
      }
    }
  }
  __syncthreads();

  #pragma unroll
  for (int rt = 0; rt < 4; ++rt)
    #pragma unroll
    for (int ct = 0; ct < 2; ++ct) acc[rt][ct] = (f32x4){0.f,0.f,0.f,0.f};

  // ---- GEMM2: h @ W2 ----
  #pragma unroll
  for (int ks = 0; ks < 4; ++ks) {
    bf16x8 af[4], bfr[2];
    #pragma unroll
    for (int rt = 0; rt < 4; ++rt) {
      int row = rt*16 + l15;
      int aidx = (row*128 + ks*32 + l4*8) ^ ((row & 7) << 3);
      af[rt] = *(const bf16x8*)(&sH[aidx]);
    }
    #pragma unroll
    for (int ct = 0; ct < 2; ++ct) {
      int col = w*32 + ct*16 + l15;
      bfr[ct] = *(const bf16x8*)(&Wt2[col*128 + ks*32 + l4*8]);
    }
    #pragma unroll
    for (int rt = 0; rt < 4; ++rt)
      #pragma unroll
      for (int ct = 0; ct < 2; ++ct)
        acc[rt][ct] = __builtin_amdgcn_mfma_f32_16x16x32_bf16(af[rt], bfr[ct], acc[rt][ct], 0, 0, 0);
  }

  // ---- epilogue 2: silu, dot W3, reduce -> spart ----
  {
    float b2r[2], w3r[2];
    #pragma unroll
    for (int ct = 0; ct < 2; ++ct) {
      int col = w*32 + ct*16 + l15;
      b2r[ct] = b2[col]; w3r[ct] = W3[col];
    }
    #pragma unroll
    for (int rt = 0; rt < 4; ++rt) {
      #pragma unroll
      for (int r = 0; r < 4; ++r) {
        float part = 0.f;
        #pragma unroll
        for (int ct = 0; ct < 2; ++ct) {
          float x = acc[rt][ct][r] + b2r[ct];
          float h = x / (1.0f + __expf(-x));
          part = fmaf(h, w3r[ct], part);
        }
        part += __shfl_xor(part, 1, 64);
        part += __shfl_xor(part, 2, 64);
        part += __shfl_xor(part, 4, 64);
        part += __shfl_xor(part, 8, 64);
        if (l15 == 0) spart[w][rt*16 + l4*4 + r] = part;
      }
    }
  }
  __syncthreads();

  // ---- scores ----
  if (t < 64) {
    float raw = spart[0][t] + spart[1][t] + spart[2][t] + spart[3][t] + b3[0];
    sScore[t] = (sDist[t] <= CUTF) ? raw : 0.0f;
  }
  __syncthreads();

  // ---- softmax + coord update: wave 0 -> edge 0, wave 1 -> edge 1 ----
  if (w < 2 && l < 32) {
    const int eh = w;
    float sc = sScore[eh*32 + l];
    float m = sc;
    #pragma unroll
    for (int mm = 1; mm < 32; mm <<= 1) m = fmaxf(m, __shfl_xor(m, mm, 64));
    m = fmaxf(m, 0.0f);
    float ex = __expf(sc - m);
    float Z = ex;
    #pragma unroll
    for (int mm = 1; mm < 32; mm <<= 1) Z += __shfl_xor(Z, mm, 64);
    Z += 8160.0f * __expf(-m);               // (E-K) zero-score tail
    float wv = ex / Z;
    swk[eh][l] = wv;
    int j = sIdx[eh*32 + l];
    float g = wv * gates[j];
    float4 cee = cen4[eBase + eh], cjj = cen4[j];
    float cx = g*(cee.x - cjj.x), cy = g*(cee.y - cjj.y), cz = g*(cee.z - cjj.z);
    #pragma unroll
    for (int mm = 1; mm < 32; mm <<= 1) {
      cx += __shfl_xor(cx, mm, 64);
      cy += __shfl_xor(cy, mm, 64);
      cz += __shfl_xor(cz, mm, 64);
    }
    if (l == 0) {
      int e = eBase + eh;
      outc[e*3+0] = ec[e*3+0] + cx;
      outc[e*3+1] = ec[e*3+1] + cy;
      outc[e*3+2] = ec[e*3+2] + cz;
    }
  }
  __syncthreads();

  // ---- weighted V + residual ----
  {
    const int eh = t >> 7, col = t & 127;
    float acc2 = 0.f;
    #pragma unroll 4
    for (int kk = 0; kk < KNB; ++kk)
      acc2 = fmaf(swk[eh][kk], bf2f(vfb[(size_t)sIdx[eh*32 + kk]*HID + col]), acc2);
    int e = eBase + eh;
    upd[(size_t)e*HID + col] = ef[(size_t)e*HID + col] + acc2;
  }
}

// ---------------- kernel 7: output projection + residual + LayerNorm, 8 edges/block ----------------
__global__ __launch_bounds__(256) void k_out(const float* __restrict__ upd,
    const float* __restrict__ ef,
    const float* __restrict__ Wo, const float* __restrict__ bo,
    const float* __restrict__ gamma, const float* __restrict__ beta,
    float* __restrict__ outf) {
  const int t = threadIdx.x;
  const int e0 = blockIdx.x * 8;
  const int o = t & 127, h = t >> 7;
  __shared__ float us[8][128];
  __shared__ float xs[8][128];
  #pragma unroll
  for (int i = 0; i < 4; ++i) {
    int ii = t + i*256;
    us[ii >> 7][ii & 127] = upd[e0*HID + ii];
  }
  __syncthreads();
  float acc[4] = {0,0,0,0};
  #pragma unroll 4
  for (int d = 0; d < 128; ++d) {
    float wo = Wo[d*128+o];
    #pragma unroll
    for (int i = 0; i < 4; ++i) acc[i] = fmaf(us[h*4+i][d], wo, acc[i]);
  }
  float bb = bo[o];
  #pragma unroll
  for (int i = 0; i < 4; ++i) {
    int e = h*4+i;
    xs[e][o] = ef[(e0+e)*HID + o] + acc[i] + bb;
  }
  __syncthreads();
  const int w = t >> 6, lane = t & 63;
  #pragma unroll
  for (int ii = 0; ii < 2; ++ii) {
    int e = w*2 + ii;
    float a = xs[e][lane], b = xs[e][64+lane];
    float s1 = a + b, s2 = a*a + b*b;
    #pragma unroll
    for (int m = 1; m < 64; m <<= 1) {
      s1 += __shfl_xor(s1, m, 64);
      s2 += __shfl_xor(s2, m, 64);
    }
    float mu = s1 * (1.0f/128.0f);
    float var = s2 * (1.0f/128.0f) - mu*mu;
    float rs = rsqrtf(var + LNEPS);
    outf[(e0+e)*HID + lane]      = (a - mu)*rs*gamma[lane]      + beta[lane];
    outf[(e0+e)*HID + 64 + lane] = (b - mu)*rs*gamma[64+lane]   + beta[64+lane];
  }
}

extern "C" void kernel_launch(void* const* d_in, const int* in_sizes, int n_in,
                              void* d_out, int out_size, void* d_ws, size_t ws_size,
                              hipStream_t stream) {
  const float* ef   = (const float*)d_in[0];
  const float* ec   = (const float*)d_in[1];
  const float* nc   = (const float*)d_in[2];
  const float* Wq   = (const float*)d_in[3];
  const float* Wk   = (const float*)d_in[4];
  const float* Wv   = (const float*)d_in[5];
  const float* W1   = (const float*)d_in[6];
  const float* b1   = (const float*)d_in[7];
  const float* W2   = (const float*)d_in[8];
  const float* b2   = (const float*)d_in[9];
  const float* W3   = (const float*)d_in[10];
  const float* b3   = (const float*)d_in[11];
  const float* Wg1  = (const float*)d_in[12];
  const float* bg1  = (const float*)d_in[13];
  const float* Wg2  = (const float*)d_in[14];
  const float* bg2  = (const float*)d_in[15];
  const float* Wo   = (const float*)d_in[16];
  const float* bo   = (const float*)d_in[17];
  const float* gamma= (const float*)d_in[18];
  const float* beta = (const float*)d_in[19];
  const float* centers = (const float*)d_in[20];
  const float* widths  = (const float*)d_in[21];
  const int*   eidx    = (const int*)d_in[22];

  float* outf = (float*)d_out;
  float* outc = outf + (size_t)E_N * HID;

  // workspace layout (16B-aligned chunks first)
  float4* cen4 = (float4*)d_ws;                        // 8192 * 16B
  u16*   kjp   = (u16*)(cen4 + E_N);                   // E * 256 bf16 (4 MB)
  u16*   vfb   = kjp + (size_t)E_N*256;                // E * 128 bf16 (2 MB)
  u16*   Wt1r  = vfb + (size_t)E_N*128;                // 128*64 bf16
  u16*   Wt2   = Wt1r + 128*64;                        // 128*128 bf16
  int*   idx   = (int*)(Wt2 + 128*128);
  float* qf    = (float*)(idx + E_N*KNB);
  float* qW1   = qf + (size_t)E_N*HID;
  float* gates = qW1 + (size_t)E_N*HID;
  float* upd   = gates + E_N;
  float* Wqc   = upd + (size_t)E_N*HID;                // 128*128 f32
  float* Wkc   = Wqc + 128*128;                        // 128*128 f32

  k_pre<<<288, 256, 0, stream>>>(W1, W2, Wq, Wk, nc, eidx, Wt1r, Wt2, Wqc, Wkc, cen4);
  k_topk<<<E_N/8, 256, 0, stream>>>(cen4, idx);
  k_qkv<<<E_N/8, 128, 0, stream>>>(ef, Wq, Wk, Wv, Wqc, Wkc, b1, Wg1, bg1, Wg2, bg2,
                                   qf, qW1, kjp, vfb, gates);
  k_mlp<<<E_N*KNB/64, 256, 0, stream>>>(idx, qf, cen4, qW1, kjp, vfb, gates, Wt1r, Wt2,
                                        W1, b2, W3, b3, centers, widths, ef, ec, upd, outc);
  k_out<<<E_N/8, 256, 0, stream>>>(upd, ef, Wo, bo, gamma, beta, outf);
}

// Round 12
// 219.660 us; speedup vs baseline: 1.3293x; 1.0140x over previous
//
#include <hip/hip_runtime.h>
#include <math.h>

#define E_N   8192
#define HID   128
#define NRAD  64
#define KNB   32
#define CUTF  10.0f
#define LNEPS 1e-5f

typedef unsigned short u16;
typedef unsigned int   u32;
typedef unsigned long long u64;
typedef __bf16 bf16x8 __attribute__((ext_vector_type(8)));
typedef u16    u16x8  __attribute__((ext_vector_type(8)));
typedef float  f32x4  __attribute__((ext_vector_type(4)));

__device__ __forceinline__ u16 f2bf(float f) {          // native HW cvt (RNE)
  __bf16 h = (__bf16)f;
  return __builtin_bit_cast(u16, h);
}
__device__ __forceinline__ float bf2f(u16 v) {
  return __uint_as_float(((u32)v) << 16);
}

__device__ __forceinline__ u64 shflx64(u64 v, int m) {
  int lo = __shfl_xor((int)(v & 0xffffffffull), m, 64);
  int hi = __shfl_xor((int)(v >> 32), m, 64);
  return ((u64)(unsigned)hi << 32) | (unsigned)lo;
}

// monotone-u32 key of squared distance; fmaf-pinned so pass1/pass2 agree bitwise
__device__ __forceinline__ u32 d2key(const float4 me, const float4 c) {
  float dot = fmaf(me.x, c.x, fmaf(me.y, c.y, me.z * c.z));
  float d2  = fmaf(-2.0f, dot, me.w + c.w);     // gram trick, as in reference
  u32 u = __float_as_uint(d2);
  return u ^ (((u32)((int)u >> 31)) | 0x80000000u);
}

// ---------------- kernel 0: merged prep (weights bf16 / fused products / centers) ----------------
__global__ __launch_bounds__(256) void k_pre(
    const float* __restrict__ W1, const float* __restrict__ W2,
    const float* __restrict__ Wq, const float* __restrict__ Wk,
    const float* __restrict__ nc, const int* __restrict__ ei,
    u16* __restrict__ Wt1r, u16* __restrict__ Wt2,
    float* __restrict__ Wqc, float* __restrict__ Wkc,
    float4* __restrict__ cen4) {
  const int b = blockIdx.x, t = threadIdx.x;
  if (b < 128) {
    if (t < 64)       Wt1r[b*64 + t]      = f2bf(W1[(256+t)*HID + b]);   // rbf rows 256..319
    else if (t < 192) Wt2[b*HID + (t-64)] = f2bf(W2[(t-64)*HID + b]);
  } else if (b < 256) {
    const int r = b - 128, o = t & 127;
    float a = 0.f;
    if (t < 128) {
      #pragma unroll 8
      for (int m = 0; m < 128; ++m) a = fmaf(Wq[r*128+m], W1[m*128+o], a);
      Wqc[r*128+o] = a;
    } else {
      #pragma unroll 8
      for (int m = 0; m < 128; ++m) a = fmaf(Wk[r*128+m], W1[(128+m)*128+o], a);
      Wkc[r*128+o] = a;
    }
  } else {
    const int e = (b - 256)*256 + t;
    if (e < E_N) {
      int a = ei[e], bb = ei[E_N + e];
      float x = (nc[a*3+0] + nc[bb*3+0]) * 0.5f;
      float y = (nc[a*3+1] + nc[bb*3+1]) * 0.5f;
      float z = (nc[a*3+2] + nc[bb*3+2]) * 0.5f;
      cen4[e] = make_float4(x, y, z, x*x + y*y + z*z);
    }
  }
}

// ---------------- kernel 2: top-K, 8 rows/block, two-pass prune + exact lex rank ----------------
__global__ __launch_bounds__(256) void k_topk(const float4* __restrict__ cen4,
                                              int* __restrict__ idxo) {
  const int row0 = blockIdx.x * 8;
  const int t = threadIdx.x;
  const int lane = t & 63, w = t >> 6;
  __shared__ __align__(16) u32 smin[8][256];   // 8 KiB
  __shared__ __align__(16) u64 comp[2048];     // 16 KiB survivor buffer
  __shared__ u32 sU[8];
  __shared__ u32 scnt, scnt_r[8];
  __shared__ u64 wred[4];
  __shared__ u64 winner;

  if (t == 0) scnt = 0;
  if (t < 8) scnt_r[t] = 0;

  float4 me[8];
  #pragma unroll
  for (int r = 0; r < 8; ++r) me[r] = cen4[row0 + r];

  // ---- pass 1: running mins for 8 rows ----
  u32 mn[8];
  #pragma unroll
  for (int r = 0; r < 8; ++r) mn[r] = 0xFFFFFFFFu;
  for (int s = 0; s < 32; ++s) {
    float4 c = cen4[t + (s << 8)];
    #pragma unroll
    for (int r = 0; r < 8; ++r) {
      u32 k = d2key(me[r], c);
      mn[r] = k < mn[r] ? k : mn[r];
    }
  }
  #pragma unroll
  for (int r = 0; r < 8; ++r) smin[r][t] = mn[r];
  __syncthreads();

  // ---- per-row bound: wave w handles rows 2w, 2w+1; in-wave radix bisect ----
  #pragma unroll
  for (int rr = 0; rr < 2; ++rr) {
    const int r = w*2 + rr;
    uint4 vv = *(const uint4*)&smin[r][lane*4];
    u32 P = 0;
    u32 rem = 31;
    #pragma unroll 1
    for (int b = 31; b >= 12; --b) {
      u32 bit = 1u << b;
      bool pm0 = ((u64)(vv.x ^ P) >> (b+1)) == 0ull;
      bool pm1 = ((u64)(vv.y ^ P) >> (b+1)) == 0ull;
      bool pm2 = ((u64)(vv.z ^ P) >> (b+1)) == 0ull;
      bool pm3 = ((u64)(vv.w ^ P) >> (b+1)) == 0ull;
      u32 c0 = (u32)__popcll(__ballot(pm0 && !(vv.x & bit)))
             + (u32)__popcll(__ballot(pm1 && !(vv.y & bit)))
             + (u32)__popcll(__ballot(pm2 && !(vv.z & bit)))
             + (u32)__popcll(__ballot(pm3 && !(vv.w & bit)));
      if (rem >= c0) { P |= bit; rem -= c0; }
    }
    if (lane == 0) sU[r] = P | 0xFFFu;
  }
  __syncthreads();

  // ---- pass 2: recompute keys, compact survivors ----
  u32 Ur[8];
  #pragma unroll
  for (int r = 0; r < 8; ++r) Ur[r] = sU[r];
  for (int s = 0; s < 32; ++s) {
    float4 c = cen4[t + (s << 8)];
    #pragma unroll
    for (int r = 0; r < 8; ++r) {
      u32 k = d2key(me[r], c);
      if (k <= Ur[r]) {
        u32 pos = atomicAdd(&scnt, 1u);
        atomicAdd(&scnt_r[r], 1u);
        if (pos < 2048u)
          comp[pos] = ((u64)r << 45) | (((u64)k) << 13) | (u32)(t + (s << 8));
      }
    }
  }
  __syncthreads();
  const int cnt = (int)scnt;

  if (cnt <= 2048) {
    u32 off[8];
    off[0] = 0;
    #pragma unroll
    for (int r = 1; r < 8; ++r) off[r] = off[r-1] + scnt_r[r-1];
    for (int i = t; i < cnt; i += 256) {
      u64 mev = comp[i];
      int rk = 0;
      int j2 = 0;
      for (; j2 + 2 <= cnt; j2 += 2) {
        ulonglong2 pr = *(const ulonglong2*)&comp[j2];
        rk += (pr.x < mev) ? 1 : 0;
        rk += (pr.y < mev) ? 1 : 0;
      }
      if (j2 < cnt) rk += (comp[j2] < mev) ? 1 : 0;
      int r = (int)(mev >> 45);
      int rank = rk - (int)off[r];
      if (rank < KNB) idxo[(row0 + r)*KNB + rank] = (int)(mev & 0x1FFFull);
    }
  } else {
    // overflow fallback (never taken statistically): exact per-row extract-min
    for (int r = 0; r < 8; ++r) {
      float4 mer = cen4[row0 + r];
      u32 taken = 0;
      for (int kk2 = 0; kk2 < KNB; ++kk2) {
        u64 lk = 0xFFFFFFFFFFFFFFFFull;
        for (int s = 0; s < 32; ++s) {
          if (taken & (1u << s)) continue;
          float4 c = cen4[t + (s << 8)];
          u64 kx = (((u64)d2key(mer, c)) << 13) | (u32)(t + (s << 8));
          lk = kx < lk ? kx : lk;
        }
        #pragma unroll
        for (int m = 1; m < 64; m <<= 1) {
          u64 o = shflx64(lk, m);
          lk = o < lk ? o : lk;
        }
        if (lane == 0) wred[w] = lk;
        __syncthreads();
        if (t == 0) {
          u64 w0 = wred[0] < wred[1] ? wred[0] : wred[1];
          u64 w1 = wred[2] < wred[3] ? wred[2] : wred[3];
          winner = w0 < w1 ? w0 : w1;
          idxo[(row0 + r)*KNB + kk2] = (int)(winner & 0x1FFFull);
        }
        __syncthreads();
        u64 jw = winner & 0x1FFFull;
        if (((u32)jw & 255u) == (u32)t) taken |= 1u << ((u32)jw >> 8);
        __syncthreads();
      }
    }
  }
}

// ---------------- kernel 3: q + fused-projection rows + packed bf16 j-side + gates ----------------
__global__ __launch_bounds__(128) void k_qkv(const float* __restrict__ ef,
    const float* __restrict__ Wq, const float* __restrict__ Wk, const float* __restrict__ Wv,
    const float* __restrict__ Wqc, const float* __restrict__ Wkc, const float* __restrict__ b1,
    const float* __restrict__ Wg1, const float* __restrict__ bg1,
    const float* __restrict__ Wg2, const float* __restrict__ bg2,
    float* __restrict__ qf, float* __restrict__ qW1,
    u16* __restrict__ kjp, u16* __restrict__ vfb, float* __restrict__ gates) {
  const int o = threadIdx.x;
  const int e0 = blockIdx.x * 8;
  __shared__ float efs[8][128];
  __shared__ float vs[8][128];
  __shared__ float gred[8][2];

  #pragma unroll
  for (int e = 0; e < 8; ++e) efs[e][o] = ef[(e0+e)*HID + o];
  __syncthreads();

  float aq[8] = {0}, ak[8] = {0}, av[8] = {0}, aqc[8] = {0}, akc[8] = {0};
  #pragma unroll 4
  for (int d = 0; d < 128; ++d) {
    float wq = Wq[d*128+o], wk = Wk[d*128+o], wv = Wv[d*128+o];
    float wc1 = Wqc[d*128+o], wc2 = Wkc[d*128+o];
    #pragma unroll
    for (int e = 0; e < 8; ++e) {
      float a = efs[e][d];
      aq[e]  = fmaf(a, wq,  aq[e]);
      ak[e]  = fmaf(a, wk,  ak[e]);
      av[e]  = fmaf(a, wv,  av[e]);
      aqc[e] = fmaf(a, wc1, aqc[e]);
      akc[e] = fmaf(a, wc2, akc[e]);
    }
  }
  float bb1 = b1[o];
  #pragma unroll
  for (int e = 0; e < 8; ++e) {
    qf[(e0+e)*HID+o]  = aq[e];
    qW1[(e0+e)*HID+o] = aqc[e] + bb1;
    kjp[(size_t)(e0+e)*256 + o]       = f2bf(akc[e]);   // kW1 part
    kjp[(size_t)(e0+e)*256 + 128 + o] = f2bf(ak[e]);    // k part (for q.k dot)
    vfb[(size_t)(e0+e)*128 + o]       = f2bf(av[e]);
    vs[e][o] = av[e];
  }
  __syncthreads();

  float ag[8] = {0};
  #pragma unroll 4
  for (int d = 0; d < 128; ++d) {
    float wg = Wg1[d*128+o];
    #pragma unroll
    for (int e = 0; e < 8; ++e) ag[e] = fmaf(vs[e][d], wg, ag[e]);
  }
  float bgo = bg1[o], w2 = Wg2[o];
  const int lane = o & 63, w = o >> 6;
  #pragma unroll
  for (int e = 0; e < 8; ++e) {
    float g = ag[e] + bgo;
    g = g / (1.0f + __expf(-g));
    float part = g * w2;
    #pragma unroll
    for (int m = 1; m < 64; m <<= 1) part += __shfl_xor(part, m, 64);
    if (lane == 0) gred[e][w] = part;
  }
  __syncthreads();
  if (o < 8) gates[e0+o] = 1.0f / (1.0f + __expf(-(gred[o][0] + gred[o][1] + bg2[0])));
}

// ---------------- kernel 5: mega (MLP + softmax + combine + Wo + LayerNorm), 4 edges/block ----------------
// 512 threads = 8 waves: wave w -> col slab (w&3)*32, row half (w>>2)*64.
__global__ __launch_bounds__(512) void k_mega(
    const int* __restrict__ idx,
    const float* __restrict__ qf,
    const float4* __restrict__ cen4,
    const float* __restrict__ qW1, const u16* __restrict__ kjp,
    const u16* __restrict__ vfb, const float* __restrict__ gates,
    const u16* __restrict__ Wt1r, const u16* __restrict__ Wt2,
    const float* __restrict__ W1,
    const float* __restrict__ b2, const float* __restrict__ W3,
    const float* __restrict__ b3,
    const float* __restrict__ centers, const float* __restrict__ widths,
    const float* __restrict__ ef, const float* __restrict__ ec,
    const float* __restrict__ Wo, const float* __restrict__ bo,
    const float* __restrict__ gamma, const float* __restrict__ beta,
    float* __restrict__ outf, float* __restrict__ outc) {
  __shared__ u16 sH[128*128];     // 32 KiB: kW1[j] tile -> in-place h tile
  __shared__ u16 sA[128*64];      // 16 KiB: rbf tile; aliased after GEMM1:
  float* spart = (float*)sA;            // [4][128] col-slab partial scores
  float* sUpd  = (float*)sA + 512;      // [4][128] updated features
  float* swk   = (float*)sA + 1024;     // [4][32]  softmax weights
  float* sred  = (float*)sA + 1152;     // [8][2]   LN partial sums
  __shared__ float sQW[4][128];   // 2 KiB
  __shared__ float sDot[128];
  __shared__ float sDist[128];
  __shared__ int   sIdx[128];

  const int t  = threadIdx.x;
  const int w  = t >> 6, l = t & 63;
  const int l15 = l & 15, l4 = l >> 4;
  const int c4 = w & 3, rh = w >> 2;
  const int rowbase = blockIdx.x * 128;
  const int eBase = rowbase >> 5;           // four edges per block

  // ---- stage: kW1[j] tile (vectorized gather -> sH), dot, dist, rbf -> sA ----
  const int srow = t >> 2, sb = t & 3;      // 128 rows x 4 threads
  const int sp = rowbase + srow;
  const int se = sp >> 5;
  const int sj = idx[sp];
  {
    const u16x8* kw = (const u16x8*)(kjp + (size_t)sj*256 + sb*32);
    #pragma unroll
    for (int g = 0; g < 4; ++g) {
      int widx = (srow*128 + sb*32 + g*8) ^ ((srow & 7) << 3);
      *(u16x8*)(&sH[widx]) = kw[g];
    }
  }
  // q.k dot: q f32 x k bf16 (packed row), 4 lanes/row
  const u16x8* kb = (const u16x8*)(kjp + (size_t)sj*256 + 128 + sb*32);
  const float4* q4 = (const float4*)(qf + (size_t)se*HID) + sb*8;
  float dt = 0.f;
  #pragma unroll
  for (int i = 0; i < 4; ++i) {
    u16x8 kv8 = kb[i];
    float4 qa = q4[i*2], qb = q4[i*2+1];
    dt += bf2f(kv8[0])*qa.x + bf2f(kv8[1])*qa.y + bf2f(kv8[2])*qa.z + bf2f(kv8[3])*qa.w
        + bf2f(kv8[4])*qb.x + bf2f(kv8[5])*qb.y + bf2f(kv8[6])*qb.z + bf2f(kv8[7])*qb.w;
  }
  dt += __shfl_xor(dt, 1, 64);
  dt += __shfl_xor(dt, 2, 64);
  // geometry
  float4 ce = cen4[se], cj = cen4[sj];
  float ddx = ce.x - cj.x, ddy = ce.y - cj.y, ddz = ce.z - cj.z;
  const float sdist = sqrtf(ddx*ddx + ddy*ddy + ddz*ddz);
  const float sincut = (sdist <= CUTF) ? 1.0f : 0.0f;
  if (sb == 0) { sDot[srow] = dt; sDist[srow] = sdist; }
  {
    u16 tmp[16];
    #pragma unroll
    for (int i4 = 0; i4 < 4; ++i4) {
      float4 cc = *(const float4*)(centers + sb*16 + i4*4);
      float4 ww = *(const float4*)(widths  + sb*16 + i4*4);
      float c4v[4] = {cc.x,cc.y,cc.z,cc.w}, w4[4] = {ww.x,ww.y,ww.z,ww.w};
      #pragma unroll
      for (int jj = 0; jj < 4; ++jj) {
        float df = sdist - c4v[jj];
        tmp[i4*4+jj] = f2bf(__expf(-w4[jj]*df*df) * sincut);
      }
    }
    #pragma unroll
    for (int g = 0; g < 2; ++g) {
      u16x8 vv;
      #pragma unroll
      for (int jj = 0; jj < 8; ++jj) vv[jj] = tmp[g*8+jj];
      int widx = (srow*64 + sb*16 + g*8) ^ ((srow & 7) << 3);
      *(u16x8*)(&sA[widx]) = vv;
    }
  }
  if (t < 512) sQW[t >> 7][t & 127] = qW1[(size_t)(eBase + (t >> 7))*HID + (t & 127)];
  if (t < 128) sIdx[t] = idx[rowbase + t];
  __syncthreads();

  f32x4 acc[4][2];
  #pragma unroll
  for (int rt = 0; rt < 4; ++rt)
    #pragma unroll
    for (int ct = 0; ct < 2; ++ct) acc[rt][ct] = (f32x4){0.f,0.f,0.f,0.f};

  // ---- GEMM1: rbf (K=64) ----
  #pragma unroll
  for (int ks = 0; ks < 2; ++ks) {
    bf16x8 af[4], bfr[2];
    #pragma unroll
    for (int rt = 0; rt < 4; ++rt) {
      int row = rh*64 + rt*16 + l15;
      int aidx = (row*64 + ks*32 + l4*8) ^ ((row & 7) << 3);
      af[rt] = *(const bf16x8*)(&sA[aidx]);
    }
    #pragma unroll
    for (int ct = 0; ct < 2; ++ct) {
      int col = c4*32 + ct*16 + l15;
      bfr[ct] = *(const bf16x8*)(&Wt1r[col*64 + ks*32 + l4*8]);
    }
    #pragma unroll
    for (int rt = 0; rt < 4; ++rt)
      #pragma unroll
      for (int ct = 0; ct < 2; ++ct)
        acc[rt][ct] = __builtin_amdgcn_mfma_f32_16x16x32_bf16(af[rt], bfr[ct], acc[rt][ct], 0, 0, 0);
  }

  // ---- epilogue 1: x = acc + qW1[e] + kW1[j](sH in-place) + dot*w320; silu -> sH ----
  {
    float w320[2];
    #pragma unroll
    for (int ct = 0; ct < 2; ++ct) {
      int col = c4*32 + ct*16 + l15;
      w320[ct] = W1[320*HID + col];
    }
    #pragma unroll
    for (int rt = 0; rt < 4; ++rt) {
      #pragma unroll
      for (int r = 0; r < 4; ++r) {
        int row = rh*64 + rt*16 + l4*4 + r;
        float dv = sDot[row];
        int eh = row >> 5;
        #pragma unroll
        for (int ct = 0; ct < 2; ++ct) {
          int col = c4*32 + ct*16 + l15;
          int hidx = (row*128 + col) ^ ((row & 7) << 3);
          float x = acc[rt][ct][r] + sQW[eh][col] + bf2f(sH[hidx]) + dv*w320[ct];
          float h = x / (1.0f + __expf(-x));
          sH[hidx] = f2bf(h);
        }
      }
    }
  }
  __syncthreads();            // all GEMM1 sA reads done; sA alias region now usable

  #pragma unroll
  for (int rt = 0; rt < 4; ++rt)
    #pragma unroll
    for (int ct = 0; ct < 2; ++ct) acc[rt][ct] = (f32x4){0.f,0.f,0.f,0.f};

  // ---- GEMM2: h @ W2 ----
  #pragma unroll
  for (int ks = 0; ks < 4; ++ks) {
    bf16x8 af[4], bfr[2];
    #pragma unroll
    for (int rt = 0; rt < 4; ++rt) {
      int row = rh*64 + rt*16 + l15;
      int aidx = (row*128 + ks*32 + l4*8) ^ ((row & 7) << 3);
      af[rt] = *(const bf16x8*)(&sH[aidx]);
    }
    #pragma unroll
    for (int ct = 0; ct < 2; ++ct) {
      int col = c4*32 + ct*16 + l15;
      bfr[ct] = *(const bf16x8*)(&Wt2[col*128 + ks*32 + l4*8]);
    }
    #pragma unroll
    for (int rt = 0; rt < 4; ++rt)
      #pragma unroll
      for (int ct = 0; ct < 2; ++ct)
        acc[rt][ct] = __builtin_amdgcn_mfma_f32_16x16x32_bf16(af[rt], bfr[ct], acc[rt][ct], 0, 0, 0);
  }

  // ---- epilogue 2: silu, dot W3, reduce over this wave's 32 cols -> spart ----
  {
    float b2r[2], w3r[2];
    #pragma unroll
    for (int ct = 0; ct < 2; ++ct) {
      int col = c4*32 + ct*16 + l15;
      b2r[ct] = b2[col]; w3r[ct] = W3[col];
    }
    #pragma unroll
    for (int rt = 0; rt < 4; ++rt) {
      #pragma unroll
      for (int r = 0; r < 4; ++r) {
        float part = 0.f;
        #pragma unroll
        for (int ct = 0; ct < 2; ++ct) {
          float x = acc[rt][ct][r] + b2r[ct];
          float h = x / (1.0f + __expf(-x));
          part = fmaf(h, w3r[ct], part);
        }
        part += __shfl_xor(part, 1, 64);
        part += __shfl_xor(part, 2, 64);
        part += __shfl_xor(part, 4, 64);
        part += __shfl_xor(part, 8, 64);
        if (l15 == 0) spart[c4*128 + rh*64 + rt*16 + l4*4 + r] = part;
      }
    }
  }
  __syncthreads();

  // ---- softmax + coord update: wave w (<4) -> edge w ----
  if (w < 4 && l < 32) {
    const int eh = w;
    const int row = eh*32 + l;
    float raw = spart[row] + spart[128 + row] + spart[256 + row] + spart[384 + row] + b3[0];
    float sc = (sDist[row] <= CUTF) ? raw : 0.0f;
    float m = sc;
    #pragma unroll
    for (int mm = 1; mm < 32; mm <<= 1) m = fmaxf(m, __shfl_xor(m, mm, 64));
    m = fmaxf(m, 0.0f);
    float ex = __expf(sc - m);
    float Z = ex;
    #pragma unroll
    for (int mm = 1; mm < 32; mm <<= 1) Z += __shfl_xor(Z, mm, 64);
    Z += 8160.0f * __expf(-m);               // (E-K) zero-score tail
    float wv = ex / Z;
    swk[eh*32 + l] = wv;
    int j = sIdx[row];
    float g = wv * gates[j];
    float4 cee = cen4[eBase + eh], cjj = cen4[j];
    float cx = g*(cee.x - cjj.x), cy = g*(cee.y - cjj.y), cz = g*(cee.z - cjj.z);
    #pragma unroll
    for (int mm = 1; mm < 32; mm <<= 1) {
      cx += __shfl_xor(cx, mm, 64);
      cy += __shfl_xor(cy, mm, 64);
      cz += __shfl_xor(cz, mm, 64);
    }
    if (l == 0) {
      int e = eBase + eh;
      outc[e*3+0] = ec[e*3+0] + cx;
      outc[e*3+1] = ec[e*3+1] + cy;
      outc[e*3+2] = ec[e*3+2] + cz;
    }
  }
  __syncthreads();

  // ---- weighted V + residual -> sUpd ----
  {
    const int eh = t >> 7, col = t & 127;
    float acc2 = 0.f;
    #pragma unroll 4
    for (int kk = 0; kk < KNB; ++kk)
      acc2 = fmaf(swk[eh*32 + kk], bf2f(vfb[(size_t)sIdx[eh*32 + kk]*HID + col]), acc2);
    sUpd[eh*128 + col] = ef[(size_t)(eBase + eh)*HID + col] + acc2;
  }
  __syncthreads();

  // ---- Wo GEMV + residual + LayerNorm ----
  {
    const int eh = t >> 7, o = t & 127;
    const int e = eBase + eh;
    float accw = 0.f;
    #pragma unroll 8
    for (int d = 0; d < 128; ++d)
      accw = fmaf(sUpd[eh*128 + d], Wo[d*128 + o], accw);
    float x = ef[(size_t)e*HID + o] + accw + bo[o];
    float s1 = x, s2 = x*x;
    #pragma unroll
    for (int m = 1; m < 64; m <<= 1) {
      s1 += __shfl_xor(s1, m, 64);
      s2 += __shfl_xor(s2, m, 64);
    }
    if (l == 0) { sred[w*2+0] = s1; sred[w*2+1] = s2; }
    __syncthreads();
    float t1 = sred[(eh*2)*2+0] + sred[(eh*2+1)*2+0];
    float t2 = sred[(eh*2)*2+1] + sred[(eh*2+1)*2+1];
    float mu = t1 * (1.0f/128.0f);
    float var = t2 * (1.0f/128.0f) - mu*mu;
    float rs = rsqrtf(var + LNEPS);
    outf[(size_t)e*HID + o] = (x - mu)*rs*gamma[o] + beta[o];
  }
}

extern "C" void kernel_launch(void* const* d_in, const int* in_sizes, int n_in,
                              void* d_out, int out_size, void* d_ws, size_t ws_size,
                              hipStream_t stream) {
  const float* ef   = (const float*)d_in[0];
  const float* ec   = (const float*)d_in[1];
  const float* nc   = (const float*)d_in[2];
  const float* Wq   = (const float*)d_in[3];
  const float* Wk   = (const float*)d_in[4];
  const float* Wv   = (const float*)d_in[5];
  const float* W1   = (const float*)d_in[6];
  const float* b1   = (const float*)d_in[7];
  const float* W2   = (const float*)d_in[8];
  const float* b2   = (const float*)d_in[9];
  const float* W3   = (const float*)d_in[10];
  const float* b3   = (const float*)d_in[11];
  const float* Wg1  = (const float*)d_in[12];
  const float* bg1  = (const float*)d_in[13];
  const float* Wg2  = (const float*)d_in[14];
  const float* bg2  = (const float*)d_in[15];
  const float* Wo   = (const float*)d_in[16];
  const float* bo   = (const float*)d_in[17];
  const float* gamma= (const float*)d_in[18];
  const float* beta = (const float*)d_in[19];
  const float* centers = (const float*)d_in[20];
  const float* widths  = (const float*)d_in[21];
  const int*   eidx    = (const int*)d_in[22];

  float* outf = (float*)d_out;
  float* outc = outf + (size_t)E_N * HID;

  // workspace layout (16B-aligned chunks first)
  float4* cen4 = (float4*)d_ws;                        // 8192 * 16B
  u16*   kjp   = (u16*)(cen4 + E_N);                   // E * 256 bf16 (4 MB)
  u16*   vfb   = kjp + (size_t)E_N*256;                // E * 128 bf16 (2 MB)
  u16*   Wt1r  = vfb + (size_t)E_N*128;                // 128*64 bf16
  u16*   Wt2   = Wt1r + 128*64;                        // 128*128 bf16
  int*   idx   = (int*)(Wt2 + 128*128);
  float* qf    = (float*)(idx + E_N*KNB);
  float* qW1   = qf + (size_t)E_N*HID;
  float* gates = qW1 + (size_t)E_N*HID;
  float* Wqc   = gates + E_N;                          // 128*128 f32
  float* Wkc   = Wqc + 128*128;                        // 128*128 f32

  k_pre<<<288, 256, 0, stream>>>(W1, W2, Wq, Wk, nc, eidx, Wt1r, Wt2, Wqc, Wkc, cen4);
  k_topk<<<E_N/8, 256, 0, stream>>>(cen4, idx);
  k_qkv<<<E_N/8, 128, 0, stream>>>(ef, Wq, Wk, Wv, Wqc, Wkc, b1, Wg1, bg1, Wg2, bg2,
                                   qf, qW1, kjp, vfb, gates);
  k_mega<<<E_N*KNB/128, 512, 0, stream>>>(idx, qf, cen4, qW1, kjp, vfb, gates, Wt1r, Wt2,
                                          W1, b2, W3, b3, centers, widths, ef, ec,
                                          Wo, bo, gamma, beta, outf, outc);
}